// Round 1
// baseline (671.628 us; speedup 1.0000x reference)
//
#include <hip/hip_runtime.h>
#include <hip/hip_bf16.h>
#include <stdint.h>

// Problem constants
#define BB 16
#define SS 2048
#define HH 1024

using bf16 = __hip_bfloat16;
typedef __attribute__((ext_vector_type(8))) short short8;
typedef __attribute__((ext_vector_type(4))) float f32x4;

typedef unsigned int __attribute__((address_space(1))) as1_uint;
typedef unsigned int __attribute__((address_space(3))) as3_uint;

// ---------------- workspace layout (bytes) ----------------
// xb   : bf16[16*2048*1024]           @ 0          (67108864)
// wqk  : bf16[2048*1024]              @ 67108864   (4194304)
// qk   : bf16[32768*2048]             @ 71303168   (134217728)  cols 0..1023 = Q/32, 1024..2047 = K
// lsum : f32[32768]                   @ 205520896  (131072)
// t    : f32[16*1024]                 @ 205651968  (65536)
// total = 205717504
static constexpr size_t WS_XB   = 0;
static constexpr size_t WS_WQK  = 67108864;
static constexpr size_t WS_QK   = 71303168;
static constexpr size_t WS_LSUM = 205520896;
static constexpr size_t WS_T    = 205651968;
static constexpr size_t WS_NEED = 205717504;

__device__ __forceinline__ void async_copy16(bf16* lds_dst, const bf16* gsrc) {
    __builtin_amdgcn_global_load_lds((const as1_uint*)gsrc, (as3_uint*)lds_dst, 16, 0, 0);
}

// ---------------- cast kernels ----------------
__global__ __launch_bounds__(256) void cast_x_kernel(const float* __restrict__ x,
                                                     bf16* __restrict__ xb, int n4) {
    int stride = gridDim.x * blockDim.x;
    for (int i = blockIdx.x * blockDim.x + threadIdx.x; i < n4; i += stride) {
        float4 v = reinterpret_cast<const float4*>(x)[i];
        union { bf16 h[4]; uint2 u; } p;
        p.h[0] = __float2bfloat16(v.x); p.h[1] = __float2bfloat16(v.y);
        p.h[2] = __float2bfloat16(v.z); p.h[3] = __float2bfloat16(v.w);
        reinterpret_cast<uint2*>(xb)[i] = p.u;
    }
}

// Wqk rows 0..1023 = W_q rows, 1024..2047 = W_k rows (flat: first 1M elems = wq, next 1M = wk)
__global__ __launch_bounds__(256) void cast_w_kernel(const float* __restrict__ wq,
                                                     const float* __restrict__ wk,
                                                     bf16* __restrict__ wqk) {
    const int n4 = (2048 * 1024) / 4;
    int stride = gridDim.x * blockDim.x;
    for (int i = blockIdx.x * blockDim.x + threadIdx.x; i < n4; i += stride) {
        int e = i * 4;
        const float* src = (e < 1024 * 1024) ? (wq + e) : (wk + e - 1024 * 1024);
        float4 v = *reinterpret_cast<const float4*>(src);
        union { bf16 h[4]; uint2 u; } p;
        p.h[0] = __float2bfloat16(v.x); p.h[1] = __float2bfloat16(v.y);
        p.h[2] = __float2bfloat16(v.z); p.h[3] = __float2bfloat16(v.w);
        reinterpret_cast<uint2*>(wqk)[i] = p.u;
    }
}

// ---------------- shared 128x128 BT-GEMM mainloop (m97 structure) ----------------
// C[128x128] = A[128xK] * B[128xK]^T, A/B row-major K-contiguous bf16, K mult of 64.
// 256 threads = 4 waves in 2x2 grid; per-wave 64x64 = 4x4 frags of 16x16x32 MFMA.
__device__ __forceinline__ void mfma_mainloop(const bf16* __restrict__ Abase, int lda,
                                              const bf16* __restrict__ Bbase, int ldb,
                                              int K, bf16* As, bf16* Bs, f32x4 acc[4][4]) {
    const int tid = threadIdx.x;
    const int wid = tid >> 6, lane = tid & 63;
    const int wm = wid >> 1, wn = wid & 1;
    const int srow = lane >> 3;          // row within 8-row staging group
    const int scol = (lane & 7) * 8;     // bf16 col offset (16B chunk)

    for (int kt = 0; kt < K; kt += 64) {
#pragma unroll
        for (int i = 0; i < 4; ++i) {
            int blkrow = (wid * 4 + i) * 8;  // wave-uniform
            async_copy16(As + blkrow * 64,
                         Abase + (size_t)(blkrow + srow) * lda + kt + scol);
            async_copy16(Bs + blkrow * 64,
                         Bbase + (size_t)(blkrow + srow) * ldb + kt + scol);
        }
        __syncthreads();
#pragma unroll
        for (int kk = 0; kk < 2; ++kk) {
            short8 a[4], b[4];
#pragma unroll
            for (int m = 0; m < 4; ++m)
                a[m] = *reinterpret_cast<const short8*>(
                    As + (wm * 64 + m * 16 + (lane & 15)) * 64 + kk * 32 + (lane >> 4) * 8);
#pragma unroll
            for (int n = 0; n < 4; ++n)
                b[n] = *reinterpret_cast<const short8*>(
                    Bs + (wn * 64 + n * 16 + (lane & 15)) * 64 + kk * 32 + (lane >> 4) * 8);
#pragma unroll
            for (int m = 0; m < 4; ++m)
#pragma unroll
                for (int n = 0; n < 4; ++n)
                    acc[m][n] = __builtin_amdgcn_mfma_f32_16x16x32_bf16(a[m], b[n], acc[m][n], 0, 0, 0);
        }
        __syncthreads();
    }
}

__device__ __forceinline__ void zero_acc(f32x4 acc[4][4]) {
#pragma unroll
    for (int m = 0; m < 4; ++m)
#pragma unroll
        for (int n = 0; n < 4; ++n) {
            acc[m][n][0] = 0.f; acc[m][n][1] = 0.f; acc[m][n][2] = 0.f; acc[m][n][3] = 0.f;
        }
}

// ---------------- G1: QK projection ----------------
// qkout[32768 x 2048] bf16 = xb[32768x1024] @ wqk^T ; cols < 1024 scaled by 1/32 (fold e/sqrt(H))
__global__ __launch_bounds__(256) void gemm_qk_proj(const bf16* __restrict__ xb,
                                                    const bf16* __restrict__ wqk,
                                                    bf16* __restrict__ qkout) {
    __shared__ bf16 As[128 * 64], Bs[128 * 64];
    f32x4 acc[4][4];
    zero_acc(acc);
    const int bx = blockIdx.x;  // n-tile 0..15
    const int by = blockIdx.y;  // m-tile 0..255
    mfma_mainloop(xb + (size_t)by * 128 * 1024, 1024,
                  wqk + (size_t)bx * 128 * 1024, 1024, 1024, As, Bs, acc);
    const float scl = (bx < 8) ? 0.03125f : 1.0f;
    const int lane = threadIdx.x & 63, wid = threadIdx.x >> 6;
    const int wm = wid >> 1, wn = wid & 1;
    const int row0 = by * 128 + wm * 64 + ((lane >> 4) << 2);
    const int col0 = bx * 128 + wn * 64 + (lane & 15);
#pragma unroll
    for (int m = 0; m < 4; ++m)
#pragma unroll
        for (int n = 0; n < 4; ++n)
#pragma unroll
            for (int r = 0; r < 4; ++r)
                qkout[(size_t)(row0 + m * 16 + r) * 2048 + col0 + n * 16] =
                    __float2bfloat16(acc[m][n][r] * scl);
}

// ---------------- pass A: energy + row sum-exp ----------------
__global__ __launch_bounds__(256) void energy_pass_a(const bf16* __restrict__ qk,
                                                     float* __restrict__ lsum) {
    __shared__ bf16 As[128 * 64], Bs[128 * 64];
    f32x4 acc[4][4];
    zero_acc(acc);
    const int bx = blockIdx.x;  // k-tile
    const int by = blockIdx.y;  // q-tile
    const int bz = blockIdx.z;  // batch
    const bf16* Ab = qk + (size_t)(bz * 2048 + by * 128) * 2048;         // Q (already /32)
    const bf16* Bb = qk + (size_t)(bz * 2048 + bx * 128) * 2048 + 1024;  // K
    mfma_mainloop(Ab, 2048, Bb, 2048, 1024, As, Bs, acc);
    const int lane = threadIdx.x & 63, wid = threadIdx.x >> 6;
    const int wm = wid >> 1;
#pragma unroll
    for (int m = 0; m < 4; ++m) {
        float s[4] = {0.f, 0.f, 0.f, 0.f};
#pragma unroll
        for (int n = 0; n < 4; ++n)
#pragma unroll
            for (int r = 0; r < 4; ++r) s[r] += __expf(acc[m][n][r]);
#pragma unroll
        for (int off = 1; off < 16; off <<= 1)
#pragma unroll
            for (int r = 0; r < 4; ++r) s[r] += __shfl_xor(s[r], off, 64);
        if ((lane & 15) == 0) {
            int rowb = bz * 2048 + by * 128 + wm * 64 + m * 16 + ((lane >> 4) << 2);
#pragma unroll
            for (int r = 0; r < 4; ++r) atomicAdd(&lsum[rowb + r], s[r]);
        }
    }
}

// ---------------- pass B: energy again + normalized column accumulation ----------------
__global__ __launch_bounds__(256) void energy_pass_b(const bf16* __restrict__ qk,
                                                     const float* __restrict__ lsum,
                                                     float* __restrict__ aw) {
    __shared__ bf16 As[128 * 64], Bs[128 * 64];
    f32x4 acc[4][4];
    zero_acc(acc);
    const int bx = blockIdx.x;
    const int by = blockIdx.y;
    const int bz = blockIdx.z;
    const bf16* Ab = qk + (size_t)(bz * 2048 + by * 128) * 2048;
    const bf16* Bb = qk + (size_t)(bz * 2048 + bx * 128) * 2048 + 1024;
    mfma_mainloop(Ab, 2048, Bb, 2048, 1024, As, Bs, acc);
    const int lane = threadIdx.x & 63, wid = threadIdx.x >> 6;
    const int wm = wid >> 1, wn = wid & 1;
    float colsum[4] = {0.f, 0.f, 0.f, 0.f};
#pragma unroll
    for (int m = 0; m < 4; ++m) {
        int rowb = bz * 2048 + by * 128 + wm * 64 + m * 16 + ((lane >> 4) << 2);
        float rl[4];
#pragma unroll
        for (int r = 0; r < 4; ++r) rl[r] = 1.0f / lsum[rowb + r];
#pragma unroll
        for (int n = 0; n < 4; ++n)
#pragma unroll
            for (int r = 0; r < 4; ++r) colsum[n] += __expf(acc[m][n][r]) * rl[r];
    }
#pragma unroll
    for (int off = 16; off < 64; off <<= 1)
#pragma unroll
        for (int n = 0; n < 4; ++n) colsum[n] += __shfl_xor(colsum[n], off, 64);
    if (lane < 16) {
        int colb = bz * 2048 + bx * 128 + wn * 64 + lane;
#pragma unroll
        for (int n = 0; n < 4; ++n)
            atomicAdd(&aw[colb + n * 16], colsum[n] * (1.0f / 2048.0f));
    }
}

// ---------------- t[b,h] = sum_k aw[b,k] * x[b,k,h] ----------------
__global__ __launch_bounds__(256) void av_x_kernel(const float* __restrict__ aw,
                                                   const float* __restrict__ x,
                                                   float* __restrict__ t) {
    const int b = blockIdx.y;
    const int kc = blockIdx.x;  // 16 chunks of 128
    const int tid = threadIdx.x;
    float4 acc = {0.f, 0.f, 0.f, 0.f};
    const int k0 = kc * 128;
#pragma unroll 4
    for (int k = k0; k < k0 + 128; ++k) {
        float w = aw[b * 2048 + k];
        float4 xv = *reinterpret_cast<const float4*>(x + (size_t)(b * 2048 + k) * 1024 + tid * 4);
        acc.x += w * xv.x; acc.y += w * xv.y; acc.z += w * xv.z; acc.w += w * xv.w;
    }
    float* tp = t + b * 1024 + tid * 4;
    atomicAdd(tp + 0, acc.x); atomicAdd(tp + 1, acc.y);
    atomicAdd(tp + 2, acc.z); atomicAdd(tp + 3, acc.w);
}

// ---------------- context[b,o] = sum_h t[b,h] * W_v[o,h] ----------------
__global__ __launch_bounds__(256) void ctx_gemv_kernel(const float* __restrict__ t,
                                                       const float* __restrict__ wv,
                                                       float* __restrict__ ctx) {
    const int b = blockIdx.y;
    const int wid = threadIdx.x >> 6, lane = threadIdx.x & 63;
    const int o = blockIdx.x * 4 + wid;
    const float4* t4 = reinterpret_cast<const float4*>(t + b * 1024);
    const float4* w4 = reinterpret_cast<const float4*>(wv + (size_t)o * 1024);
    float s = 0.f;
#pragma unroll
    for (int j = lane; j < 256; j += 64) {
        float4 a = t4[j], w = w4[j];
        s += a.x * w.x + a.y * w.y + a.z * w.z + a.w * w.w;
    }
#pragma unroll
    for (int off = 1; off < 64; off <<= 1) s += __shfl_xor(s, off, 64);
    if (lane == 0) ctx[b * 1024 + o] = s;
}

__global__ void ws_too_small_kernel(float* out) {
    if (threadIdx.x == 0 && blockIdx.x == 0) out[0] = 12345.0f;
}

extern "C" void kernel_launch(void* const* d_in, const int* in_sizes, int n_in,
                              void* d_out, int out_size, void* d_ws, size_t ws_size,
                              hipStream_t stream) {
    const float* x  = (const float*)d_in[0];
    const float* wq = (const float*)d_in[1];
    const float* wk = (const float*)d_in[2];
    const float* wv = (const float*)d_in[3];
    float* out = (float*)d_out;
    float* ctx = out;           // 16*1024
    float* aw  = out + 16384;   // 16*2048

    if (ws_size < WS_NEED) {  // sentinel so this failure mode is distinguishable
        hipMemsetAsync(d_out, 0, (size_t)out_size * sizeof(float), stream);
        ws_too_small_kernel<<<1, 64, 0, stream>>>(out);
        return;
    }

    char* ws = (char*)d_ws;
    bf16* xb   = (bf16*)(ws + WS_XB);
    bf16* wqk  = (bf16*)(ws + WS_WQK);
    bf16* qk   = (bf16*)(ws + WS_QK);
    float* lsum = (float*)(ws + WS_LSUM);
    float* t    = (float*)(ws + WS_T);

    // zero accumulators + output (harness poisons once; we must re-init every call)
    hipMemsetAsync(d_out, 0, (size_t)out_size * sizeof(float), stream);
    hipMemsetAsync(lsum, 0, 131072 + 65536, stream);  // lsum + t contiguous

    cast_x_kernel<<<2048, 256, 0, stream>>>(x, xb, (BB * SS * HH) / 4);
    cast_w_kernel<<<512, 256, 0, stream>>>(wq, wk, wqk);

    dim3 g1(16, 256);
    gemm_qk_proj<<<g1, 256, 0, stream>>>(xb, wqk, qk);

    dim3 g2(16, 16, 16);
    energy_pass_a<<<g2, 256, 0, stream>>>(qk, lsum);
    energy_pass_b<<<g2, 256, 0, stream>>>(qk, lsum, aw);

    dim3 g4a(16, 16);
    av_x_kernel<<<g4a, 256, 0, stream>>>(aw, x, t);

    dim3 g4b(256, 16);
    ctx_gemv_kernel<<<g4b, 256, 0, stream>>>(t, wv, ctx);
}

// Round 2
// 445.367 us; speedup vs baseline: 1.5080x; 1.5080x over previous
//
#include <hip/hip_runtime.h>
#include <hip/hip_bf16.h>
#include <stdint.h>

// Problem constants
#define BB 16
#define SS 2048
#define HH 1024

using bf16 = __hip_bfloat16;
typedef __attribute__((ext_vector_type(8))) short short8;
typedef __attribute__((ext_vector_type(4))) float f32x4;

typedef unsigned int __attribute__((address_space(1))) as1_uint;
typedef unsigned int __attribute__((address_space(3))) as3_uint;

// ---------------- workspace layout (bytes) ----------------
// xb   : bf16[16*2048*1024]    @ 0          (67108864)
// G    : bf16[32768*1024]      @ 67108864   (67108864)   G = x @ (Wq^T Wk)/32, bf16
// P    : fp8 [32768*2048]      @ 134217728  (67108864)   P = exp(E/32), e4m3
//   (aliased inside P region, dead before P is written:)
//   wqT : bf16[1024*1024]      @ 134217728  (2097152)
//   wkT : bf16[1024*1024]      @ 136314880  (2097152)
//   Mt  : bf16[1024*1024]      @ 138412032  (2097152)    Mt[j][i] = M[i][j]/32
// lsum : f32[32768]            @ 201326592  (131072)
// t    : f32[16*1024]          @ 201457664  (65536)
static constexpr size_t WS_XB   = 0;
static constexpr size_t WS_G    = 67108864;
static constexpr size_t WS_P    = 134217728;
static constexpr size_t WS_WQT  = 134217728;
static constexpr size_t WS_WKT  = 136314880;
static constexpr size_t WS_MT   = 138412032;
static constexpr size_t WS_LSUM = 201326592;
static constexpr size_t WS_T    = 201457664;
static constexpr size_t WS_NEED = 201523200;

__device__ __forceinline__ void async_copy16(bf16* lds_dst, const bf16* gsrc) {
    __builtin_amdgcn_global_load_lds((const as1_uint*)gsrc, (as3_uint*)lds_dst, 16, 0, 0);
}

// ---------------- fp8 e4m3 encode/decode ----------------
__device__ __forceinline__ unsigned char f32_to_e4m3(float x) {
#if __has_builtin(__builtin_amdgcn_cvt_pk_fp8_f32)
    return (unsigned char)(__builtin_amdgcn_cvt_pk_fp8_f32(x, x, 0, false) & 0xff);
#else
    // x > 0, finite, < 448 here
    if (x >= 0.015625f) {  // normal: 2^-6 .. 448
        union { float f; unsigned u; } v; v.f = x;
        int e = (v.u >> 23) & 0xff;
        unsigned m = v.u & 0x7fffff;
        unsigned mant = m >> 20;
        unsigned rem = m & 0xfffff;
        mant += (rem > 0x80000u) || (rem == 0x80000u && (mant & 1));
        int oe = e - 120;
        if (mant == 8) { mant = 0; oe += 1; }
        return (unsigned char)((oe << 3) | mant);
    }
    int code = (int)rintf(x * 512.0f);  // denormal (and 8 -> 2^-6 exactly)
    return (unsigned char)code;
#endif
}

__device__ __forceinline__ float e4m3_to_f32(unsigned char b) {
#if __has_builtin(__builtin_amdgcn_cvt_pk_f32_fp8)
    auto v = __builtin_amdgcn_cvt_pk_f32_fp8((int)b, false);
    return v[0];
#else
    int e = (b >> 3) & 15, m = b & 7;
    if (e) { union { unsigned u; float f; } v; v.u = ((unsigned)(e + 120) << 23) | ((unsigned)m << 20); return v.f; }
    return (float)m * 0.001953125f;
#endif
}

// ---------------- cast x -> bf16 ----------------
__global__ __launch_bounds__(256) void cast_x_kernel(const float* __restrict__ x,
                                                     bf16* __restrict__ xb, int n4) {
    int stride = gridDim.x * blockDim.x;
    for (int i = blockIdx.x * blockDim.x + threadIdx.x; i < n4; i += stride) {
        float4 v = reinterpret_cast<const float4*>(x)[i];
        union { bf16 h[4]; uint2 u; } p;
        p.h[0] = __float2bfloat16(v.x); p.h[1] = __float2bfloat16(v.y);
        p.h[2] = __float2bfloat16(v.z); p.h[3] = __float2bfloat16(v.w);
        reinterpret_cast<uint2*>(xb)[i] = p.u;
    }
}

// ---------------- transpose-cast W (1024x1024 f32, (o,i)) -> WT bf16 (i,o) ----------------
__global__ __launch_bounds__(256) void transpose_w_kernel(const float* __restrict__ wq,
                                                          const float* __restrict__ wk,
                                                          bf16* __restrict__ wqT,
                                                          bf16* __restrict__ wkT) {
    __shared__ float tile[64][65];
    const float* src = blockIdx.z ? wk : wq;
    bf16* dst = blockIdx.z ? wkT : wqT;
    const int o0 = blockIdx.y * 64, i0 = blockIdx.x * 64;
    const int tr = threadIdx.x >> 4;        // 0..15
    const int tc = (threadIdx.x & 15) * 4;  // 0..60
#pragma unroll
    for (int k = 0; k < 4; ++k) {
        float4 v = *reinterpret_cast<const float4*>(src + (size_t)(o0 + tr + k * 16) * 1024 + i0 + tc);
        tile[tr + k * 16][tc + 0] = v.x; tile[tr + k * 16][tc + 1] = v.y;
        tile[tr + k * 16][tc + 2] = v.z; tile[tr + k * 16][tc + 3] = v.w;
    }
    __syncthreads();
#pragma unroll
    for (int k = 0; k < 4; ++k) {
        int ri = tr + k * 16;
        union { bf16 h[4]; uint2 u; } p;
#pragma unroll
        for (int j = 0; j < 4; ++j) p.h[j] = __float2bfloat16(tile[tc + j][ri]);
        *reinterpret_cast<uint2*>(dst + (size_t)(i0 + ri) * 1024 + o0 + tc) = p.u;
    }
}

// ---------------- shared 128x128 BT-GEMM mainloop (m97 structure) ----------------
// C[128x128] = A[128xK] * B[128xK]^T, A/B row-major K-contiguous bf16, K mult of 64.
__device__ __forceinline__ void mfma_mainloop(const bf16* __restrict__ Abase, int lda,
                                              const bf16* __restrict__ Bbase, int ldb,
                                              int K, bf16* As, bf16* Bs, f32x4 acc[4][4]) {
    const int tid = threadIdx.x;
    const int wid = tid >> 6, lane = tid & 63;
    const int wm = wid >> 1, wn = wid & 1;
    const int srow = lane >> 3;
    const int scol = (lane & 7) * 8;

    for (int kt = 0; kt < K; kt += 64) {
#pragma unroll
        for (int i = 0; i < 4; ++i) {
            int blkrow = (wid * 4 + i) * 8;
            async_copy16(As + blkrow * 64,
                         Abase + (size_t)(blkrow + srow) * lda + kt + scol);
            async_copy16(Bs + blkrow * 64,
                         Bbase + (size_t)(blkrow + srow) * ldb + kt + scol);
        }
        __syncthreads();
#pragma unroll
        for (int kk = 0; kk < 2; ++kk) {
            short8 a[4], b[4];
#pragma unroll
            for (int m = 0; m < 4; ++m)
                a[m] = *reinterpret_cast<const short8*>(
                    As + (wm * 64 + m * 16 + (lane & 15)) * 64 + kk * 32 + (lane >> 4) * 8);
#pragma unroll
            for (int n = 0; n < 4; ++n)
                b[n] = *reinterpret_cast<const short8*>(
                    Bs + (wn * 64 + n * 16 + (lane & 15)) * 64 + kk * 32 + (lane >> 4) * 8);
#pragma unroll
            for (int m = 0; m < 4; ++m)
#pragma unroll
                for (int n = 0; n < 4; ++n)
                    acc[m][n] = __builtin_amdgcn_mfma_f32_16x16x32_bf16(a[m], b[n], acc[m][n], 0, 0, 0);
        }
        __syncthreads();
    }
}

__device__ __forceinline__ void zero_acc(f32x4 acc[4][4]) {
#pragma unroll
    for (int m = 0; m < 4; ++m)
#pragma unroll
        for (int n = 0; n < 4; ++n) {
            acc[m][n][0] = 0.f; acc[m][n][1] = 0.f; acc[m][n][2] = 0.f; acc[m][n][3] = 0.f;
        }
}

// ---------------- Mt[j][i] = (1/32) * sum_o Wk[o,j]*Wq[o,i]  (= M[i][j]/32) ----------------
__global__ __launch_bounds__(256) void gemm_mt(const bf16* __restrict__ wkT,
                                               const bf16* __restrict__ wqT,
                                               bf16* __restrict__ Mt) {
    __shared__ bf16 As[128 * 64], Bs[128 * 64];
    f32x4 acc[4][4];
    zero_acc(acc);
    const int bx = blockIdx.x, by = blockIdx.y;
    mfma_mainloop(wkT + (size_t)by * 128 * 1024, 1024,
                  wqT + (size_t)bx * 128 * 1024, 1024, 1024, As, Bs, acc);
    const int lane = threadIdx.x & 63, wid = threadIdx.x >> 6;
    const int wm = wid >> 1, wn = wid & 1;
    const int row0 = by * 128 + wm * 64 + ((lane >> 4) << 2);
    const int col0 = bx * 128 + wn * 64 + (lane & 15);
#pragma unroll
    for (int m = 0; m < 4; ++m)
#pragma unroll
        for (int n = 0; n < 4; ++n)
#pragma unroll
            for (int r = 0; r < 4; ++r)
                Mt[(size_t)(row0 + m * 16 + r) * 1024 + col0 + n * 16] =
                    __float2bfloat16(acc[m][n][r] * 0.03125f);
}

// ---------------- G = xb @ Mt^T  (32768x1024) ----------------
__global__ __launch_bounds__(256) void gemm_g(const bf16* __restrict__ xb,
                                              const bf16* __restrict__ Mt,
                                              bf16* __restrict__ G) {
    __shared__ bf16 As[128 * 64], Bs[128 * 64];
    f32x4 acc[4][4];
    zero_acc(acc);
    const int bx = blockIdx.x, by = blockIdx.y;
    mfma_mainloop(xb + (size_t)by * 128 * 1024, 1024,
                  Mt + (size_t)bx * 128 * 1024, 1024, 1024, As, Bs, acc);
    const int lane = threadIdx.x & 63, wid = threadIdx.x >> 6;
    const int wm = wid >> 1, wn = wid & 1;
    const int row0 = by * 128 + wm * 64 + ((lane >> 4) << 2);
    const int col0 = bx * 128 + wn * 64 + (lane & 15);
#pragma unroll
    for (int m = 0; m < 4; ++m)
#pragma unroll
        for (int n = 0; n < 4; ++n)
#pragma unroll
            for (int r = 0; r < 4; ++r)
                G[(size_t)(row0 + m * 16 + r) * 1024 + col0 + n * 16] =
                    __float2bfloat16(acc[m][n][r]);
}

// ---------------- energy: E = G @ xb^T (once), P = fp8(exp(E)), lsum += rowsum(dec(P)) ----------------
__global__ __launch_bounds__(256) void energy_fused(const bf16* __restrict__ G,
                                                    const bf16* __restrict__ xb,
                                                    unsigned char* __restrict__ P,
                                                    float* __restrict__ lsum) {
    __shared__ bf16 As[128 * 64], Bs[128 * 64];
    f32x4 acc[4][4];
    zero_acc(acc);
    const int bx = blockIdx.x;  // k-tile
    const int by = blockIdx.y;  // q-tile
    const int bz = blockIdx.z;  // batch
    mfma_mainloop(G + (size_t)(bz * 2048 + by * 128) * 1024, 1024,
                  xb + (size_t)(bz * 2048 + bx * 128) * 1024, 1024, 1024, As, Bs, acc);
    const int lane = threadIdx.x & 63, wid = threadIdx.x >> 6;
    const int wm = wid >> 1, wn = wid & 1;
    const int q0 = bz * 2048 + by * 128 + wm * 64 + ((lane >> 4) << 2);  // global q row
    const int k0 = bx * 128 + wn * 64 + (lane & 15);                     // col within batch
#pragma unroll
    for (int m = 0; m < 4; ++m) {
        float s[4] = {0.f, 0.f, 0.f, 0.f};
#pragma unroll
        for (int n = 0; n < 4; ++n)
#pragma unroll
            for (int r = 0; r < 4; ++r) {
                float e = __expf(acc[m][n][r]);
                unsigned char c = f32_to_e4m3(e);
                P[(size_t)(q0 + m * 16 + r) * 2048 + k0 + n * 16] = c;
                s[r] += e4m3_to_f32(c);  // sum the QUANTIZED values -> bias cancels in aw
            }
#pragma unroll
        for (int off = 1; off < 16; off <<= 1)
#pragma unroll
            for (int r = 0; r < 4; ++r) s[r] += __shfl_xor(s[r], off, 64);
        if ((lane & 15) == 0) {
#pragma unroll
            for (int r = 0; r < 4; ++r) atomicAdd(&lsum[q0 + m * 16 + r], s[r]);
        }
    }
}

// ---------------- aw[b,k] = (1/S) sum_q dec(P[b,q,k]) / lsum[b,q] ----------------
__global__ __launch_bounds__(256) void colsum_kernel(const unsigned char* __restrict__ P,
                                                     const float* __restrict__ lsum,
                                                     float* __restrict__ aw) {
    const int b = blockIdx.y, qc = blockIdx.x, t = threadIdx.x;
    float acc[8] = {0.f, 0.f, 0.f, 0.f, 0.f, 0.f, 0.f, 0.f};
    const unsigned char* base = P + (size_t)(b * 2048 + qc * 128) * 2048 + t * 8;
    const float* ls = lsum + b * 2048 + qc * 128;
    for (int q = 0; q < 128; ++q) {
        float w = 1.0f / ls[q];
        uint2 v = *reinterpret_cast<const uint2*>(base + (size_t)q * 2048);
#if __has_builtin(__builtin_amdgcn_cvt_pk_f32_fp8)
        auto p0 = __builtin_amdgcn_cvt_pk_f32_fp8((int)v.x, false);
        auto p1 = __builtin_amdgcn_cvt_pk_f32_fp8((int)v.x, true);
        auto p2 = __builtin_amdgcn_cvt_pk_f32_fp8((int)v.y, false);
        auto p3 = __builtin_amdgcn_cvt_pk_f32_fp8((int)v.y, true);
        acc[0] += p0[0] * w; acc[1] += p0[1] * w;
        acc[2] += p1[0] * w; acc[3] += p1[1] * w;
        acc[4] += p2[0] * w; acc[5] += p2[1] * w;
        acc[6] += p3[0] * w; acc[7] += p3[1] * w;
#else
        unsigned char by8[8];
        *reinterpret_cast<uint2*>(by8) = v;
#pragma unroll
        for (int j = 0; j < 8; ++j) acc[j] += e4m3_to_f32(by8[j]) * w;
#endif
    }
#pragma unroll
    for (int j = 0; j < 8; ++j)
        atomicAdd(&aw[b * 2048 + t * 8 + j], acc[j] * (1.0f / 2048.0f));
}

// ---------------- t[b,h] = sum_k aw[b,k] * x[b,k,h] ----------------
__global__ __launch_bounds__(256) void av_x_kernel(const float* __restrict__ aw,
                                                   const float* __restrict__ x,
                                                   float* __restrict__ t) {
    const int b = blockIdx.y;
    const int kc = blockIdx.x;
    const int tid = threadIdx.x;
    float4 acc = {0.f, 0.f, 0.f, 0.f};
    const int k0 = kc * 128;
#pragma unroll 4
    for (int k = k0; k < k0 + 128; ++k) {
        float w = aw[b * 2048 + k];
        float4 xv = *reinterpret_cast<const float4*>(x + (size_t)(b * 2048 + k) * 1024 + tid * 4);
        acc.x += w * xv.x; acc.y += w * xv.y; acc.z += w * xv.z; acc.w += w * xv.w;
    }
    float* tp = t + b * 1024 + tid * 4;
    atomicAdd(tp + 0, acc.x); atomicAdd(tp + 1, acc.y);
    atomicAdd(tp + 2, acc.z); atomicAdd(tp + 3, acc.w);
}

// ---------------- context[b,o] = sum_h t[b,h] * W_v[o,h] ----------------
__global__ __launch_bounds__(256) void ctx_gemv_kernel(const float* __restrict__ t,
                                                       const float* __restrict__ wv,
                                                       float* __restrict__ ctx) {
    const int b = blockIdx.y;
    const int wid = threadIdx.x >> 6, lane = threadIdx.x & 63;
    const int o = blockIdx.x * 4 + wid;
    const float4* t4 = reinterpret_cast<const float4*>(t + b * 1024);
    const float4* w4 = reinterpret_cast<const float4*>(wv + (size_t)o * 1024);
    float s = 0.f;
#pragma unroll
    for (int j = lane; j < 256; j += 64) {
        float4 a = t4[j], w = w4[j];
        s += a.x * w.x + a.y * w.y + a.z * w.z + a.w * w.w;
    }
#pragma unroll
    for (int off = 1; off < 64; off <<= 1) s += __shfl_xor(s, off, 64);
    if (lane == 0) ctx[b * 1024 + o] = s;
}

__global__ void ws_too_small_kernel(float* out) {
    if (threadIdx.x == 0 && blockIdx.x == 0) out[0] = 12345.0f;
}

extern "C" void kernel_launch(void* const* d_in, const int* in_sizes, int n_in,
                              void* d_out, int out_size, void* d_ws, size_t ws_size,
                              hipStream_t stream) {
    const float* x  = (const float*)d_in[0];
    const float* wq = (const float*)d_in[1];
    const float* wk = (const float*)d_in[2];
    const float* wv = (const float*)d_in[3];
    float* out = (float*)d_out;
    float* ctx = out;           // 16*1024
    float* aw  = out + 16384;   // 16*2048

    if (ws_size < WS_NEED) {
        hipMemsetAsync(d_out, 0, (size_t)out_size * sizeof(float), stream);
        ws_too_small_kernel<<<1, 64, 0, stream>>>(out);
        return;
    }

    char* ws = (char*)d_ws;
    bf16* xb   = (bf16*)(ws + WS_XB);
    bf16* G    = (bf16*)(ws + WS_G);
    unsigned char* P = (unsigned char*)(ws + WS_P);
    bf16* wqT  = (bf16*)(ws + WS_WQT);
    bf16* wkT  = (bf16*)(ws + WS_WKT);
    bf16* Mt   = (bf16*)(ws + WS_MT);
    float* lsum = (float*)(ws + WS_LSUM);
    float* t    = (float*)(ws + WS_T);

    hipMemsetAsync(d_out, 0, (size_t)out_size * sizeof(float), stream);
    hipMemsetAsync(lsum, 0, 131072 + 65536, stream);  // lsum + t contiguous

    cast_x_kernel<<<2048, 256, 0, stream>>>(x, xb, (BB * SS * HH) / 4);
    transpose_w_kernel<<<dim3(16, 16, 2), 256, 0, stream>>>(wq, wk, wqT, wkT);

    gemm_mt<<<dim3(8, 8), 256, 0, stream>>>(wkT, wqT, Mt);
    gemm_g<<<dim3(8, 256), 256, 0, stream>>>(xb, Mt, G);

    energy_fused<<<dim3(16, 16, 16), 256, 0, stream>>>(G, xb, P, lsum);
    colsum_kernel<<<dim3(16, 16), 256, 0, stream>>>(P, lsum, aw);

    av_x_kernel<<<dim3(16, 16), 256, 0, stream>>>(aw, x, t);
    ctx_gemv_kernel<<<dim3(256, 16), 256, 0, stream>>>(t, wv, ctx);
}

// Round 3
// 368.403 us; speedup vs baseline: 1.8231x; 1.2089x over previous
//
#include <hip/hip_runtime.h>
#include <hip/hip_bf16.h>
#include <stdint.h>

// Problem constants
#define BB 16
#define SS 2048
#define HH 1024

using bf16 = __hip_bfloat16;
typedef __attribute__((ext_vector_type(8))) short short8;
typedef __attribute__((ext_vector_type(4))) float f32x4;

typedef unsigned int __attribute__((address_space(1))) as1_uint;
typedef unsigned int __attribute__((address_space(3))) as3_uint;

// ---------------- workspace layout (bytes) ----------------
static constexpr size_t WS_XB   = 0;          // bf16[16*2048*1024]
static constexpr size_t WS_G    = 67108864;   // bf16[32768*1024]
static constexpr size_t WS_P    = 134217728;  // fp8 [32768*2048]
static constexpr size_t WS_WQT  = 134217728;  // aliased, dead before P written
static constexpr size_t WS_WKT  = 136314880;
static constexpr size_t WS_MT   = 138412032;
static constexpr size_t WS_LSUM = 201326592;  // f32[32768]
static constexpr size_t WS_T    = 201457664;  // f32[16*1024]
static constexpr size_t WS_NEED = 201523200;

__device__ __forceinline__ void async_copy16(bf16* lds_dst, const bf16* gsrc) {
    __builtin_amdgcn_global_load_lds((const as1_uint*)gsrc, (as3_uint*)lds_dst, 16, 0, 0);
}

// ---------------- fp8 e4m3 encode/decode ----------------
__device__ __forceinline__ unsigned char f32_to_e4m3(float x) {
#if __has_builtin(__builtin_amdgcn_cvt_pk_fp8_f32)
    return (unsigned char)(__builtin_amdgcn_cvt_pk_fp8_f32(x, x, 0, false) & 0xff);
#else
    if (x >= 0.015625f) {
        union { float f; unsigned u; } v; v.f = x;
        int e = (v.u >> 23) & 0xff;
        unsigned m = v.u & 0x7fffff;
        unsigned mant = m >> 20;
        unsigned rem = m & 0xfffff;
        mant += (rem > 0x80000u) || (rem == 0x80000u && (mant & 1));
        int oe = e - 120;
        if (mant == 8) { mant = 0; oe += 1; }
        return (unsigned char)((oe << 3) | mant);
    }
    int code = (int)rintf(x * 512.0f);
    return (unsigned char)code;
#endif
}

__device__ __forceinline__ float e4m3_to_f32(unsigned char b) {
#if __has_builtin(__builtin_amdgcn_cvt_pk_f32_fp8)
    auto v = __builtin_amdgcn_cvt_pk_f32_fp8((int)b, false);
    return v[0];
#else
    int e = (b >> 3) & 15, m = b & 7;
    if (e) { union { unsigned u; float f; } v; v.u = ((unsigned)(e + 120) << 23) | ((unsigned)m << 20); return v.f; }
    return (float)m * 0.001953125f;
#endif
}

// ---------------- cast x -> bf16 ----------------
__global__ __launch_bounds__(256) void cast_x_kernel(const float* __restrict__ x,
                                                     bf16* __restrict__ xb, int n4) {
    int stride = gridDim.x * blockDim.x;
    for (int i = blockIdx.x * blockDim.x + threadIdx.x; i < n4; i += stride) {
        float4 v = reinterpret_cast<const float4*>(x)[i];
        union { bf16 h[4]; uint2 u; } p;
        p.h[0] = __float2bfloat16(v.x); p.h[1] = __float2bfloat16(v.y);
        p.h[2] = __float2bfloat16(v.z); p.h[3] = __float2bfloat16(v.w);
        reinterpret_cast<uint2*>(xb)[i] = p.u;
    }
}

// ---------------- transpose-cast W -> WT bf16 (i,o) ----------------
__global__ __launch_bounds__(256) void transpose_w_kernel(const float* __restrict__ wq,
                                                          const float* __restrict__ wk,
                                                          bf16* __restrict__ wqT,
                                                          bf16* __restrict__ wkT) {
    __shared__ float tile[64][65];
    const float* src = blockIdx.z ? wk : wq;
    bf16* dst = blockIdx.z ? wkT : wqT;
    const int o0 = blockIdx.y * 64, i0 = blockIdx.x * 64;
    const int tr = threadIdx.x >> 4;
    const int tc = (threadIdx.x & 15) * 4;
#pragma unroll
    for (int k = 0; k < 4; ++k) {
        float4 v = *reinterpret_cast<const float4*>(src + (size_t)(o0 + tr + k * 16) * 1024 + i0 + tc);
        tile[tr + k * 16][tc + 0] = v.x; tile[tr + k * 16][tc + 1] = v.y;
        tile[tr + k * 16][tc + 2] = v.z; tile[tr + k * 16][tc + 3] = v.w;
    }
    __syncthreads();
#pragma unroll
    for (int k = 0; k < 4; ++k) {
        int ri = tr + k * 16;
        union { bf16 h[4]; uint2 u; } p;
#pragma unroll
        for (int j = 0; j < 4; ++j) p.h[j] = __float2bfloat16(tile[tc + j][ri]);
        *reinterpret_cast<uint2*>(dst + (size_t)(i0 + ri) * 1024 + o0 + tc) = p.u;
    }
}

// ================= old 128x128 mainloop (kept for the tiny gemm_mt) =================
__device__ __forceinline__ void mfma_mainloop(const bf16* __restrict__ Abase, int lda,
                                              const bf16* __restrict__ Bbase, int ldb,
                                              int K, bf16* As, bf16* Bs, f32x4 acc[4][4]) {
    const int tid = threadIdx.x;
    const int wid = tid >> 6, lane = tid & 63;
    const int wm = wid >> 1, wn = wid & 1;
    const int srow = lane >> 3;
    const int scol = (lane & 7) * 8;
    for (int kt = 0; kt < K; kt += 64) {
#pragma unroll
        for (int i = 0; i < 4; ++i) {
            int blkrow = (wid * 4 + i) * 8;
            async_copy16(As + blkrow * 64, Abase + (size_t)(blkrow + srow) * lda + kt + scol);
            async_copy16(Bs + blkrow * 64, Bbase + (size_t)(blkrow + srow) * ldb + kt + scol);
        }
        __syncthreads();
#pragma unroll
        for (int kk = 0; kk < 2; ++kk) {
            short8 a[4], b[4];
#pragma unroll
            for (int m = 0; m < 4; ++m)
                a[m] = *reinterpret_cast<const short8*>(
                    As + (wm * 64 + m * 16 + (lane & 15)) * 64 + kk * 32 + (lane >> 4) * 8);
#pragma unroll
            for (int n = 0; n < 4; ++n)
                b[n] = *reinterpret_cast<const short8*>(
                    Bs + (wn * 64 + n * 16 + (lane & 15)) * 64 + kk * 32 + (lane >> 4) * 8);
#pragma unroll
            for (int m = 0; m < 4; ++m)
#pragma unroll
                for (int n = 0; n < 4; ++n)
                    acc[m][n] = __builtin_amdgcn_mfma_f32_16x16x32_bf16(a[m], b[n], acc[m][n], 0, 0, 0);
        }
        __syncthreads();
    }
}

// Mt[j][i] = (1/32) * sum_o Wk[o,j]*Wq[o,i]
__global__ __launch_bounds__(256) void gemm_mt(const bf16* __restrict__ wkT,
                                               const bf16* __restrict__ wqT,
                                               bf16* __restrict__ Mt) {
    __shared__ bf16 As[128 * 64], Bs[128 * 64];
    f32x4 acc[4][4];
#pragma unroll
    for (int m = 0; m < 4; ++m)
#pragma unroll
        for (int n = 0; n < 4; ++n) { acc[m][n][0]=0.f; acc[m][n][1]=0.f; acc[m][n][2]=0.f; acc[m][n][3]=0.f; }
    const int bx = blockIdx.x, by = blockIdx.y;
    mfma_mainloop(wkT + (size_t)by * 128 * 1024, 1024,
                  wqT + (size_t)bx * 128 * 1024, 1024, 1024, As, Bs, acc);
    const int lane = threadIdx.x & 63, wid = threadIdx.x >> 6;
    const int wm = wid >> 1, wn = wid & 1;
    const int row0 = by * 128 + wm * 64 + ((lane >> 4) << 2);
    const int col0 = bx * 128 + wn * 64 + (lane & 15);
#pragma unroll
    for (int m = 0; m < 4; ++m)
#pragma unroll
        for (int n = 0; n < 4; ++n)
#pragma unroll
            for (int r = 0; r < 4; ++r)
                Mt[(size_t)(row0 + m * 16 + r) * 1024 + col0 + n * 16] =
                    __float2bfloat16(acc[m][n][r] * 0.03125f);
}

// ================= 256x256 8-phase mainloop (T2+T3+T4+T5) =================
// C[256x256] = A[256x1024] * B[256x1024]^T, both row-major K-contiguous bf16, ld=1024.
// 512 threads = 8 waves (2M x 4N). Per-wave C: 128x64 = 8x4 frags of 16x16 (K=32 MFMA).
// LDS per buffer: As 32KB (row-reordered: As_row = qm*128 + wm*64 + j; logical row = wm*128+qm*64+j)
//                 Bs 32KB (Bs_row = qn*128 + wn*32 + s;  logical row = wn*64+qn*32+s)
// Double buffered = 128KB. XOR swizzle: lds_byte ^= ((lds_row&7)<<4), applied on the
// per-lane GLOBAL source during global_load_lds (linear LDS dest) and on ds_read addr.
// Quadrant order per tile: (qm,qn) = (0,0),(0,1),(1,0),(1,1).
// Region free schedule -> stage schedule (regions are 16KB, 2 loads/thread each):
//   ph0: stage B-qn1 of tile t+1 (other buf; freed at t-1 boundary)
//   ph1: stage A-qm1 of tile t+1 (other buf; freed at t-1 boundary)
//   ph2: stage A-qm0 of tile t+2 (cur buf; freed by ph1 end barrier)
//   ph3: stage B-qn0 of tile t+2 (cur buf; freed by ph2 end barrier)
// Boundary: s_waitcnt vmcnt(4) (the 4 newest = tile t+2 pieces) + barrier.
static constexpr int NT256 = 16;  // K=1024 / BK=64

__device__ __forceinline__ void stage_A256(char* As_base, int qm,
                                           const bf16* __restrict__ Ag, int kt) {
    const int tid = threadIdx.x;
    const int wid = tid >> 6;
#pragma unroll
    for (int i = 0; i < 2; ++i) {
        int beta = (i * 512 + tid) * 16;        // region-relative byte 0..16383
        int rho  = beta >> 7;                   // region row 0..127
        int c    = beta & 127;
        int cs   = c ^ ((rho & 7) << 4);        // swizzled source column byte
        int wm_r = rho >> 6, j = rho & 63;
        int grow = wm_r * 128 + qm * 64 + j;    // logical A row within 256-block
        const bf16* src = Ag + (size_t)grow * 1024 + kt * 64 + (cs >> 1);
        char* dst = As_base + qm * 16384 + i * 8192 + wid * 1024;  // wave-uniform; lane -> +lane*16
        async_copy16((bf16*)dst, src);
    }
}

__device__ __forceinline__ void stage_B256(char* Bs_base, int qn,
                                           const bf16* __restrict__ Bg, int kt) {
    const int tid = threadIdx.x;
    const int wid = tid >> 6;
#pragma unroll
    for (int i = 0; i < 2; ++i) {
        int beta = (i * 512 + tid) * 16;
        int rho  = beta >> 7;
        int c    = beta & 127;
        int cs   = c ^ ((rho & 7) << 4);
        int wn_r = rho >> 5, s = rho & 31;
        int grow = wn_r * 64 + qn * 32 + s;     // logical B row (output col) within 256-block
        const bf16* src = Bg + (size_t)grow * 1024 + kt * 64 + (cs >> 1);
        char* dst = Bs_base + qn * 16384 + i * 8192 + wid * 1024;
        async_copy16((bf16*)dst, src);
    }
}

__device__ __forceinline__ void gemm256_mainloop(const bf16* __restrict__ Ag,
                                                 const bf16* __restrict__ Bg,
                                                 char* lds, f32x4 acc[8][4]) {
    const int tid = threadIdx.x;
    const int lane = tid & 63;
    const int wm = (tid >> 6) >> 2;   // 0..1
    const int wn = (tid >> 6) & 3;    // 0..3

#pragma unroll
    for (int m = 0; m < 8; ++m)
#pragma unroll
        for (int n = 0; n < 4; ++n) { acc[m][n][0]=0.f; acc[m][n][1]=0.f; acc[m][n][2]=0.f; acc[m][n][3]=0.f; }

    char* A0 = lds;            char* B0 = lds + 32768;
    char* A1 = lds + 65536;    char* B1 = lds + 98304;

    // Prologue: tile0 fully + tile1 {A-qm0, B-qn0}; then wait for tile0 (8 oldest of 12).
    stage_A256(A0, 0, Ag, 0);
    stage_A256(A0, 1, Ag, 0);
    stage_B256(B0, 0, Bg, 0);
    stage_B256(B0, 1, Bg, 0);
    stage_A256(A1, 0, Ag, 1);
    stage_B256(B1, 0, Bg, 1);
    asm volatile("s_waitcnt vmcnt(4)" ::: "memory");
    __builtin_amdgcn_s_barrier();

#pragma unroll 1
    for (int t = 0; t < NT256; ++t) {
        char* As  = (t & 1) ? A1 : A0;
        char* Bs  = (t & 1) ? B1 : B0;
        char* Aso = (t & 1) ? A0 : A1;
        char* Bso = (t & 1) ? B0 : B1;
#pragma unroll
        for (int ph = 0; ph < 4; ++ph) {
            const int qm = ph >> 1, qn = ph & 1;
            short8 a[4][2], b[2][2];
#pragma unroll
            for (int mi = 0; mi < 4; ++mi)
#pragma unroll
                for (int kk = 0; kk < 2; ++kk) {
                    int row = qm * 128 + wm * 64 + mi * 16 + (lane & 15);
                    int col = kk * 64 + (lane >> 4) * 16;
                    int off = (row * 128 + col) ^ ((row & 7) << 4);
                    a[mi][kk] = *reinterpret_cast<const short8*>(As + off);
                }
#pragma unroll
            for (int ni = 0; ni < 2; ++ni)
#pragma unroll
                for (int kk = 0; kk < 2; ++kk) {
                    int row = qn * 128 + wn * 32 + ni * 16 + (lane & 15);
                    int col = kk * 64 + (lane >> 4) * 16;
                    int off = (row * 128 + col) ^ ((row & 7) << 4);
                    b[ni][kk] = *reinterpret_cast<const short8*>(Bs + off);
                }
            // stage per region-free schedule (wave-uniform guards)
            if (ph == 0)      { if (t + 1 < NT256) stage_B256(Bso, 1, Bg, t + 1); }
            else if (ph == 1) { if (t + 1 < NT256) stage_A256(Aso, 1, Ag, t + 1); }
            else if (ph == 2) { if (t + 2 < NT256) stage_A256(As,  0, Ag, t + 2); }
            else              { if (t + 2 < NT256) stage_B256(Bs,  0, Bg, t + 2); }
            __builtin_amdgcn_s_barrier();           // mid barrier (phase alignment)
            __builtin_amdgcn_s_setprio(1);
#pragma unroll
            for (int mi = 0; mi < 4; ++mi)
#pragma unroll
                for (int ni = 0; ni < 2; ++ni)
#pragma unroll
                    for (int kk = 0; kk < 2; ++kk)
                        acc[qm * 4 + mi][qn * 2 + ni] =
                            __builtin_amdgcn_mfma_f32_16x16x32_bf16(
                                a[mi][kk], b[ni][kk], acc[qm * 4 + mi][qn * 2 + ni], 0, 0, 0);
            __builtin_amdgcn_s_setprio(0);
            // all my LDS reads must be complete before the freeing barrier
            asm volatile("s_waitcnt lgkmcnt(0)" ::: "memory");
            __builtin_amdgcn_s_barrier();           // end barrier: frees this phase's regions
        }
        if (t + 2 < NT256) asm volatile("s_waitcnt vmcnt(4)" ::: "memory");
        else               asm volatile("s_waitcnt vmcnt(0)" ::: "memory");
        __builtin_amdgcn_s_barrier();               // tile boundary: next tile fully landed
    }
}

// ---------------- G = xb @ Mt^T  (32768x1024), 256² 8-phase ----------------
__global__ __launch_bounds__(512, 2) void gemm_g256(const bf16* __restrict__ xb,
                                                    const bf16* __restrict__ Mt,
                                                    bf16* __restrict__ G) {
    extern __shared__ char lds[];
    f32x4 acc[8][4];
    const int bx = blockIdx.x, by = blockIdx.y;
    gemm256_mainloop(xb + (size_t)by * 256 * 1024, Mt + (size_t)bx * 256 * 1024, lds, acc);
    const int lane = threadIdx.x & 63, wid = threadIdx.x >> 6;
    const int wm = wid >> 2, wn = wid & 3;
    const int row0 = by * 256 + wm * 128 + ((lane >> 4) << 2);
    const int col0 = bx * 256 + wn * 64 + (lane & 15);
#pragma unroll
    for (int mi = 0; mi < 8; ++mi)
#pragma unroll
        for (int ni = 0; ni < 4; ++ni)
#pragma unroll
            for (int r = 0; r < 4; ++r)
                G[(size_t)(row0 + mi * 16 + r) * 1024 + col0 + ni * 16] =
                    __float2bfloat16(acc[mi][ni][r]);
}

// ---------------- energy: E = G @ xb^T, P = fp8(exp(E)), lsum += rowsum(dec(P)) ----------------
__global__ __launch_bounds__(512, 2) void energy_fused256(const bf16* __restrict__ G,
                                                          const bf16* __restrict__ xb,
                                                          unsigned char* __restrict__ P,
                                                          float* __restrict__ lsum) {
    extern __shared__ char lds[];
    f32x4 acc[8][4];
    const int bx = blockIdx.x, by = blockIdx.y, bz = blockIdx.z;
    gemm256_mainloop(G + (size_t)(bz * 2048 + by * 256) * 1024,
                     xb + (size_t)(bz * 2048 + bx * 256) * 1024, lds, acc);
    const int lane = threadIdx.x & 63, wid = threadIdx.x >> 6;
    const int wm = wid >> 2, wn = wid & 3;
    const int q0 = bz * 2048 + by * 256 + wm * 128 + ((lane >> 4) << 2);
    const int k0 = bx * 256 + wn * 64 + (lane & 15);
#pragma unroll
    for (int mi = 0; mi < 8; ++mi) {
        float s[4] = {0.f, 0.f, 0.f, 0.f};
#pragma unroll
        for (int ni = 0; ni < 4; ++ni)
#pragma unroll
            for (int r = 0; r < 4; ++r) {
                float e = __expf(acc[mi][ni][r]);
                unsigned char c = f32_to_e4m3(e);
                P[(size_t)(q0 + mi * 16 + r) * 2048 + k0 + ni * 16] = c;
                s[r] += e4m3_to_f32(c);
            }
#pragma unroll
        for (int off = 1; off < 16; off <<= 1)
#pragma unroll
            for (int r = 0; r < 4; ++r) s[r] += __shfl_xor(s[r], off, 64);
        if ((lane & 15) == 0) {
#pragma unroll
            for (int r = 0; r < 4; ++r) atomicAdd(&lsum[q0 + mi * 16 + r], s[r]);
        }
    }
}

// ---------------- aw[b,k] = (1/S) sum_q dec(P[b,q,k]) / lsum[b,q] ----------------
__global__ __launch_bounds__(256) void colsum_kernel(const unsigned char* __restrict__ P,
                                                     const float* __restrict__ lsum,
                                                     float* __restrict__ aw) {
    const int b = blockIdx.y, qc = blockIdx.x, t = threadIdx.x;
    float acc[8] = {0.f, 0.f, 0.f, 0.f, 0.f, 0.f, 0.f, 0.f};
    const unsigned char* base = P + (size_t)(b * 2048 + qc * 128) * 2048 + t * 8;
    const float* ls = lsum + b * 2048 + qc * 128;
    for (int q = 0; q < 128; ++q) {
        float w = 1.0f / ls[q];
        uint2 v = *reinterpret_cast<const uint2*>(base + (size_t)q * 2048);
#if __has_builtin(__builtin_amdgcn_cvt_pk_f32_fp8)
        auto p0 = __builtin_amdgcn_cvt_pk_f32_fp8((int)v.x, false);
        auto p1 = __builtin_amdgcn_cvt_pk_f32_fp8((int)v.x, true);
        auto p2 = __builtin_amdgcn_cvt_pk_f32_fp8((int)v.y, false);
        auto p3 = __builtin_amdgcn_cvt_pk_f32_fp8((int)v.y, true);
        acc[0] += p0[0] * w; acc[1] += p0[1] * w;
        acc[2] += p1[0] * w; acc[3] += p1[1] * w;
        acc[4] += p2[0] * w; acc[5] += p2[1] * w;
        acc[6] += p3[0] * w; acc[7] += p3[1] * w;
#else
        unsigned char by8[8];
        *reinterpret_cast<uint2*>(by8) = v;
#pragma unroll
        for (int j = 0; j < 8; ++j) acc[j] += e4m3_to_f32(by8[j]) * w;
#endif
    }
#pragma unroll
    for (int j = 0; j < 8; ++j)
        atomicAdd(&aw[b * 2048 + t * 8 + j], acc[j] * (1.0f / 2048.0f));
}

// ---------------- t[b,h] = sum_k aw[b,k] * x[b,k,h] ----------------
__global__ __launch_bounds__(256) void av_x_kernel(const float* __restrict__ aw,
                                                   const float* __restrict__ x,
                                                   float* __restrict__ t) {
    const int b = blockIdx.y;
    const int kc = blockIdx.x;
    const int tid = threadIdx.x;
    float4 acc = {0.f, 0.f, 0.f, 0.f};
    const int k0 = kc * 128;
#pragma unroll 4
    for (int k = k0; k < k0 + 128; ++k) {
        float w = aw[b * 2048 + k];
        float4 xv = *reinterpret_cast<const float4*>(x + (size_t)(b * 2048 + k) * 1024 + tid * 4);
        acc.x += w * xv.x; acc.y += w * xv.y; acc.z += w * xv.z; acc.w += w * xv.w;
    }
    float* tp = t + b * 1024 + tid * 4;
    atomicAdd(tp + 0, acc.x); atomicAdd(tp + 1, acc.y);
    atomicAdd(tp + 2, acc.z); atomicAdd(tp + 3, acc.w);
}

// ---------------- context[b,o] = sum_h t[b,h] * W_v[o,h] ----------------
__global__ __launch_bounds__(256) void ctx_gemv_kernel(const float* __restrict__ t,
                                                       const float* __restrict__ wv,
                                                       float* __restrict__ ctx) {
    const int b = blockIdx.y;
    const int wid = threadIdx.x >> 6, lane = threadIdx.x & 63;
    const int o = blockIdx.x * 4 + wid;
    const float4* t4 = reinterpret_cast<const float4*>(t + b * 1024);
    const float4* w4 = reinterpret_cast<const float4*>(wv + (size_t)o * 1024);
    float s = 0.f;
#pragma unroll
    for (int j = lane; j < 256; j += 64) {
        float4 a = t4[j], w = w4[j];
        s += a.x * w.x + a.y * w.y + a.z * w.z + a.w * w.w;
    }
#pragma unroll
    for (int off = 1; off < 64; off <<= 1) s += __shfl_xor(s, off, 64);
    if (lane == 0) ctx[b * 1024 + o] = s;
}

__global__ void ws_too_small_kernel(float* out) {
    if (threadIdx.x == 0 && blockIdx.x == 0) out[0] = 12345.0f;
}

extern "C" void kernel_launch(void* const* d_in, const int* in_sizes, int n_in,
                              void* d_out, int out_size, void* d_ws, size_t ws_size,
                              hipStream_t stream) {
    const float* x  = (const float*)d_in[0];
    const float* wq = (const float*)d_in[1];
    const float* wk = (const float*)d_in[2];
    const float* wv = (const float*)d_in[3];
    float* out = (float*)d_out;
    float* ctx = out;           // 16*1024
    float* aw  = out + 16384;   // 16*2048

    if (ws_size < WS_NEED) {
        hipMemsetAsync(d_out, 0, (size_t)out_size * sizeof(float), stream);
        ws_too_small_kernel<<<1, 64, 0, stream>>>(out);
        return;
    }

    char* ws = (char*)d_ws;
    bf16* xb   = (bf16*)(ws + WS_XB);
    bf16* G    = (bf16*)(ws + WS_G);
    unsigned char* P = (unsigned char*)(ws + WS_P);
    bf16* wqT  = (bf16*)(ws + WS_WQT);
    bf16* wkT  = (bf16*)(ws + WS_WKT);
    bf16* Mt   = (bf16*)(ws + WS_MT);
    float* lsum = (float*)(ws + WS_LSUM);
    float* t    = (float*)(ws + WS_T);

    hipMemsetAsync(d_out, 0, (size_t)out_size * sizeof(float), stream);
    hipMemsetAsync(lsum, 0, 131072 + 65536, stream);  // lsum + t contiguous

    cast_x_kernel<<<2048, 256, 0, stream>>>(x, xb, (BB * SS * HH) / 4);
    transpose_w_kernel<<<dim3(16, 16, 2), 256, 0, stream>>>(wq, wk, wqT, wkT);

    gemm_mt<<<dim3(8, 8), 256, 0, stream>>>(wkT, wqT, Mt);
    gemm_g256<<<dim3(4, 128), 512, 131072, stream>>>(xb, Mt, G);

    energy_fused256<<<dim3(8, 8, 16), 512, 131072, stream>>>(G, xb, P, lsum);
    colsum_kernel<<<dim3(16, 16), 256, 0, stream>>>(P, lsum, aw);

    av_x_kernel<<<dim3(16, 16), 256, 0, stream>>>(aw, x, t);
    ctx_gemv_kernel<<<dim3(256, 16), 256, 0, stream>>>(t, wv, ctx);
}

// Round 4
// 324.361 us; speedup vs baseline: 2.0706x; 1.1358x over previous
//
#include <hip/hip_runtime.h>
#include <hip/hip_bf16.h>
#include <stdint.h>

// Problem constants
#define BB 16
#define SS 2048
#define HH 1024

using bf16 = __hip_bfloat16;
typedef __attribute__((ext_vector_type(8))) short short8;
typedef __attribute__((ext_vector_type(4))) float f32x4;

typedef unsigned int __attribute__((address_space(1))) as1_uint;
typedef unsigned int __attribute__((address_space(3))) as3_uint;

// ---------------- workspace layout (bytes) ----------------
static constexpr size_t WS_XB   = 0;          // bf16[16*2048*1024]
static constexpr size_t WS_G    = 67108864;   // bf16[32768*1024]
static constexpr size_t WS_P    = 134217728;  // fp8 [32768*2048]
static constexpr size_t WS_WQT  = 134217728;  // aliased, dead before P written
static constexpr size_t WS_WKT  = 136314880;
static constexpr size_t WS_MT   = 138412032;
static constexpr size_t WS_LSUM = 201326592;  // f32[32768]
static constexpr size_t WS_T    = 201457664;  // f32[16*1024]
static constexpr size_t WS_NEED = 201523200;

__device__ __forceinline__ void async_copy16(bf16* lds_dst, const bf16* gsrc) {
    __builtin_amdgcn_global_load_lds((const as1_uint*)gsrc, (as3_uint*)lds_dst, 16, 0, 0);
}

__device__ __forceinline__ float bf2f(unsigned short u) {
    union { unsigned i; float f; } v; v.i = (unsigned)u << 16; return v.f;
}

// ---------------- fp8 e4m3 encode/decode ----------------
__device__ __forceinline__ unsigned char f32_to_e4m3(float x) {
#if __has_builtin(__builtin_amdgcn_cvt_pk_fp8_f32)
    return (unsigned char)(__builtin_amdgcn_cvt_pk_fp8_f32(x, x, 0, false) & 0xff);
#else
    if (x >= 0.015625f) {
        union { float f; unsigned u; } v; v.f = x;
        int e = (v.u >> 23) & 0xff;
        unsigned m = v.u & 0x7fffff;
        unsigned mant = m >> 20;
        unsigned rem = m & 0xfffff;
        mant += (rem > 0x80000u) || (rem == 0x80000u && (mant & 1));
        int oe = e - 120;
        if (mant == 8) { mant = 0; oe += 1; }
        return (unsigned char)((oe << 3) | mant);
    }
    int code = (int)rintf(x * 512.0f);
    return (unsigned char)code;
#endif
}

__device__ __forceinline__ float e4m3_to_f32(unsigned char b) {
#if __has_builtin(__builtin_amdgcn_cvt_pk_f32_fp8)
    auto v = __builtin_amdgcn_cvt_pk_f32_fp8((int)b, false);
    return v[0];
#else
    int e = (b >> 3) & 15, m = b & 7;
    if (e) { union { unsigned u; float f; } v; v.u = ((unsigned)(e + 120) << 23) | ((unsigned)m << 20); return v.f; }
    return (float)m * 0.001953125f;
#endif
}

// ---------------- cast x -> bf16 ----------------
__global__ __launch_bounds__(256) void cast_x_kernel(const float* __restrict__ x,
                                                     bf16* __restrict__ xb, int n4) {
    int stride = gridDim.x * blockDim.x;
    for (int i = blockIdx.x * blockDim.x + threadIdx.x; i < n4; i += stride) {
        float4 v = reinterpret_cast<const float4*>(x)[i];
        union { bf16 h[4]; uint2 u; } p;
        p.h[0] = __float2bfloat16(v.x); p.h[1] = __float2bfloat16(v.y);
        p.h[2] = __float2bfloat16(v.z); p.h[3] = __float2bfloat16(v.w);
        reinterpret_cast<uint2*>(xb)[i] = p.u;
    }
}

// ---------------- transpose-cast W -> WT bf16 (i,o) ----------------
__global__ __launch_bounds__(256) void transpose_w_kernel(const float* __restrict__ wq,
                                                          const float* __restrict__ wk,
                                                          bf16* __restrict__ wqT,
                                                          bf16* __restrict__ wkT) {
    __shared__ float tile[64][65];
    const float* src = blockIdx.z ? wk : wq;
    bf16* dst = blockIdx.z ? wkT : wqT;
    const int o0 = blockIdx.y * 64, i0 = blockIdx.x * 64;
    const int tr = threadIdx.x >> 4;
    const int tc = (threadIdx.x & 15) * 4;
#pragma unroll
    for (int k = 0; k < 4; ++k) {
        float4 v = *reinterpret_cast<const float4*>(src + (size_t)(o0 + tr + k * 16) * 1024 + i0 + tc);
        tile[tr + k * 16][tc + 0] = v.x; tile[tr + k * 16][tc + 1] = v.y;
        tile[tr + k * 16][tc + 2] = v.z; tile[tr + k * 16][tc + 3] = v.w;
    }
    __syncthreads();
#pragma unroll
    for (int k = 0; k < 4; ++k) {
        int ri = tr + k * 16;
        union { bf16 h[4]; uint2 u; } p;
#pragma unroll
        for (int j = 0; j < 4; ++j) p.h[j] = __float2bfloat16(tile[tc + j][ri]);
        *reinterpret_cast<uint2*>(dst + (size_t)(i0 + ri) * 1024 + o0 + tc) = p.u;
    }
}

// ---------------- gemm_mt64: Mt[j][i] = (1/32) sum_o Wk[o,j]*Wq[o,i], 64x64 tiles ----------------
__global__ __launch_bounds__(256) void gemm_mt64(const bf16* __restrict__ wkT,
                                                 const bf16* __restrict__ wqT,
                                                 bf16* __restrict__ Mt) {
    __shared__ bf16 As[64 * 64], Bs[64 * 64];
    f32x4 acc[2][2];
#pragma unroll
    for (int m = 0; m < 2; ++m)
#pragma unroll
        for (int n = 0; n < 2; ++n) { acc[m][n][0]=0.f; acc[m][n][1]=0.f; acc[m][n][2]=0.f; acc[m][n][3]=0.f; }
    const int tid = threadIdx.x, wid = tid >> 6, lane = tid & 63;
    const int wm = wid >> 1, wn = wid & 1;
    const int srow = lane >> 3, scol = (lane & 7) * 8;
    const bf16* Ab = wkT + (size_t)blockIdx.y * 64 * 1024;
    const bf16* Bb = wqT + (size_t)blockIdx.x * 64 * 1024;
    for (int kt = 0; kt < 1024; kt += 64) {
#pragma unroll
        for (int i = 0; i < 2; ++i) {
            int row0 = i * 32 + wid * 8;  // wave-uniform
            async_copy16(As + row0 * 64, Ab + (size_t)(row0 + srow) * 1024 + kt + scol);
            async_copy16(Bs + row0 * 64, Bb + (size_t)(row0 + srow) * 1024 + kt + scol);
        }
        __syncthreads();
#pragma unroll
        for (int kk = 0; kk < 2; ++kk) {
            short8 a[2], b[2];
#pragma unroll
            for (int m = 0; m < 2; ++m)
                a[m] = *reinterpret_cast<const short8*>(
                    As + (wm * 32 + m * 16 + (lane & 15)) * 64 + kk * 32 + (lane >> 4) * 8);
#pragma unroll
            for (int n = 0; n < 2; ++n)
                b[n] = *reinterpret_cast<const short8*>(
                    Bs + (wn * 32 + n * 16 + (lane & 15)) * 64 + kk * 32 + (lane >> 4) * 8);
#pragma unroll
            for (int m = 0; m < 2; ++m)
#pragma unroll
                for (int n = 0; n < 2; ++n)
                    acc[m][n] = __builtin_amdgcn_mfma_f32_16x16x32_bf16(a[m], b[n], acc[m][n], 0, 0, 0);
        }
        __syncthreads();
    }
    const int row0 = blockIdx.y * 64 + wm * 32 + ((lane >> 4) << 2);
    const int col0 = blockIdx.x * 64 + wn * 32 + (lane & 15);
#pragma unroll
    for (int m = 0; m < 2; ++m)
#pragma unroll
        for (int n = 0; n < 2; ++n)
#pragma unroll
            for (int r = 0; r < 4; ++r)
                Mt[(size_t)(row0 + m * 16 + r) * 1024 + col0 + n * 16] =
                    __float2bfloat16(acc[m][n][r] * 0.03125f);
}

// ================= 256x256 8-phase mainloop, snake-order reads (T2+T3+T4+T5) =================
// C[256x256] = A[256x1024] * B[256x1024]^T, row-major K-contiguous bf16, ld=1024.
// 512 threads = 8 waves (2M x 4N); per-wave C 128x64. Quadrants per K-tile in SNAKE order
// (0,0)->(0,1)->(1,1)->(1,0): A-half and both B-halves held in regs -> 24 b128/wave/K-tile.
// Staging schedule identical to the verified r3 schedule:
//   ph0: stage B-qn1[t+1] (other buf)   ph1: stage A-qm1[t+1] (other buf)
//   ph2: stage A-qm0[t+2] (cur buf)     ph3: stage B-qn0[t+2] (cur buf)
// Boundary: vmcnt(4) folded before ph3's end barrier.
static constexpr int NT256 = 16;  // K=1024 / BK=64

__device__ __forceinline__ void stage_A256(char* As_base, int qm,
                                           const bf16* __restrict__ Ag, int kt) {
    const int tid = threadIdx.x;
    const int wid = tid >> 6;
#pragma unroll
    for (int i = 0; i < 2; ++i) {
        int beta = (i * 512 + tid) * 16;        // region-relative byte
        int rho  = beta >> 7;                   // region row 0..127
        int c    = beta & 127;
        int cs   = c ^ ((rho & 7) << 4);        // pre-swizzled source column byte
        int wm_r = rho >> 6, j = rho & 63;
        int grow = wm_r * 128 + qm * 64 + j;    // logical A row within 256-block
        const bf16* src = Ag + (size_t)grow * 1024 + kt * 64 + (cs >> 1);
        char* dst = As_base + qm * 16384 + i * 8192 + wid * 1024;  // wave-uniform; +lane*16 implicit
        async_copy16((bf16*)dst, src);
    }
}

__device__ __forceinline__ void stage_B256(char* Bs_base, int qn,
                                           const bf16* __restrict__ Bg, int kt) {
    const int tid = threadIdx.x;
    const int wid = tid >> 6;
#pragma unroll
    for (int i = 0; i < 2; ++i) {
        int beta = (i * 512 + tid) * 16;
        int rho  = beta >> 7;
        int c    = beta & 127;
        int cs   = c ^ ((rho & 7) << 4);
        int wn_r = rho >> 5, s = rho & 31;
        int grow = wn_r * 64 + qn * 32 + s;     // logical B row (output col) within 256-block
        const bf16* src = Bg + (size_t)grow * 1024 + kt * 64 + (cs >> 1);
        char* dst = Bs_base + qn * 16384 + i * 8192 + wid * 1024;
        async_copy16((bf16*)dst, src);
    }
}

__device__ __forceinline__ void gemm256_mainloop(const bf16* __restrict__ Ag,
                                                 const bf16* __restrict__ Bg,
                                                 char* lds, f32x4 acc[8][4]) {
    const int tid = threadIdx.x;
    const int lane = tid & 63;
    const int wm = (tid >> 6) >> 2;   // 0..1
    const int wn = (tid >> 6) & 3;    // 0..3

#pragma unroll
    for (int m = 0; m < 8; ++m)
#pragma unroll
        for (int n = 0; n < 4; ++n) { acc[m][n][0]=0.f; acc[m][n][1]=0.f; acc[m][n][2]=0.f; acc[m][n][3]=0.f; }

    char* A0 = lds;            char* B0 = lds + 32768;
    char* A1 = lds + 65536;    char* B1 = lds + 98304;

    // Prologue: tile0 fully, then tile1 {A-qm0, B-qn0}; wait for the 8 oldest (tile0).
    stage_A256(A0, 0, Ag, 0);
    stage_B256(B0, 0, Bg, 0);
    stage_B256(B0, 1, Bg, 0);
    stage_A256(A0, 1, Ag, 0);
    stage_A256(A1, 0, Ag, 1);
    stage_B256(B1, 0, Bg, 1);
    asm volatile("s_waitcnt vmcnt(4)" ::: "memory");
    __builtin_amdgcn_s_barrier();

    short8 a[4][2], b0[2][2], b1[2][2];

#pragma unroll 1
    for (int t = 0; t < NT256; ++t) {
        char* As  = (t & 1) ? A1 : A0;
        char* Bs  = (t & 1) ? B1 : B0;
        char* Aso = (t & 1) ? A0 : A1;
        char* Bso = (t & 1) ? B0 : B1;

        // ---- ph0: quadrant (0,0). Read A-half0 (8) + B-half0 (4). ----
#pragma unroll
        for (int mi = 0; mi < 4; ++mi)
#pragma unroll
            for (int kk = 0; kk < 2; ++kk) {
                int row = wm * 64 + mi * 16 + (lane & 15);          // qm=0
                int off = (row * 128 + kk * 64 + (lane >> 4) * 16) ^ ((row & 7) << 4);
                a[mi][kk] = *reinterpret_cast<const short8*>(As + off);
            }
#pragma unroll
        for (int ni = 0; ni < 2; ++ni)
#pragma unroll
            for (int kk = 0; kk < 2; ++kk) {
                int row = wn * 32 + ni * 16 + (lane & 15);          // qn=0
                int off = (row * 128 + kk * 64 + (lane >> 4) * 16) ^ ((row & 7) << 4);
                b0[ni][kk] = *reinterpret_cast<const short8*>(Bs + off);
            }
        if (t + 1 < NT256) stage_B256(Bso, 1, Bg, t + 1);
        __builtin_amdgcn_s_barrier();
        asm volatile("s_waitcnt lgkmcnt(0)" ::: "memory");
        __builtin_amdgcn_s_setprio(1);
#pragma unroll
        for (int mi = 0; mi < 4; ++mi)
#pragma unroll
            for (int ni = 0; ni < 2; ++ni)
#pragma unroll
                for (int kk = 0; kk < 2; ++kk)
                    acc[mi][ni] = __builtin_amdgcn_mfma_f32_16x16x32_bf16(
                        a[mi][kk], b0[ni][kk], acc[mi][ni], 0, 0, 0);
        __builtin_amdgcn_s_setprio(0);
        __builtin_amdgcn_s_barrier();

        // ---- ph1: quadrant (0,1). Read B-half1 (4); reuse a. ----
#pragma unroll
        for (int ni = 0; ni < 2; ++ni)
#pragma unroll
            for (int kk = 0; kk < 2; ++kk) {
                int row = 128 + wn * 32 + ni * 16 + (lane & 15);    // qn=1
                int off = (row * 128 + kk * 64 + (lane >> 4) * 16) ^ ((row & 7) << 4);
                b1[ni][kk] = *reinterpret_cast<const short8*>(Bs + off);
            }
        if (t + 1 < NT256) stage_A256(Aso, 1, Ag, t + 1);
        __builtin_amdgcn_s_barrier();
        asm volatile("s_waitcnt lgkmcnt(0)" ::: "memory");
        __builtin_amdgcn_s_setprio(1);
#pragma unroll
        for (int mi = 0; mi < 4; ++mi)
#pragma unroll
            for (int ni = 0; ni < 2; ++ni)
#pragma unroll
                for (int kk = 0; kk < 2; ++kk)
                    acc[mi][2 + ni] = __builtin_amdgcn_mfma_f32_16x16x32_bf16(
                        a[mi][kk], b1[ni][kk], acc[mi][2 + ni], 0, 0, 0);
        __builtin_amdgcn_s_setprio(0);
        __builtin_amdgcn_s_barrier();

        // ---- ph2: quadrant (1,1). Read A-half1 (8); reuse b1. ----
#pragma unroll
        for (int mi = 0; mi < 4; ++mi)
#pragma unroll
            for (int kk = 0; kk < 2; ++kk) {
                int row = 128 + wm * 64 + mi * 16 + (lane & 15);    // qm=1
                int off = (row * 128 + kk * 64 + (lane >> 4) * 16) ^ ((row & 7) << 4);
                a[mi][kk] = *reinterpret_cast<const short8*>(As + off);
            }
        if (t + 2 < NT256) stage_A256(As, 0, Ag, t + 2);
        __builtin_amdgcn_s_barrier();
        asm volatile("s_waitcnt lgkmcnt(0)" ::: "memory");
        __builtin_amdgcn_s_setprio(1);
#pragma unroll
        for (int mi = 0; mi < 4; ++mi)
#pragma unroll
            for (int ni = 0; ni < 2; ++ni)
#pragma unroll
                for (int kk = 0; kk < 2; ++kk)
                    acc[4 + mi][2 + ni] = __builtin_amdgcn_mfma_f32_16x16x32_bf16(
                        a[mi][kk], b1[ni][kk], acc[4 + mi][2 + ni], 0, 0, 0);
        __builtin_amdgcn_s_setprio(0);
        __builtin_amdgcn_s_barrier();

        // ---- ph3: quadrant (1,0). No reads; reuse a + held b0. ----
        if (t + 2 < NT256) stage_B256(Bs, 0, Bg, t + 2);
        __builtin_amdgcn_s_barrier();
        __builtin_amdgcn_s_setprio(1);
#pragma unroll
        for (int mi = 0; mi < 4; ++mi)
#pragma unroll
            for (int ni = 0; ni < 2; ++ni)
#pragma unroll
                for (int kk = 0; kk < 2; ++kk)
                    acc[4 + mi][ni] = __builtin_amdgcn_mfma_f32_16x16x32_bf16(
                        a[mi][kk], b0[ni][kk], acc[4 + mi][ni], 0, 0, 0);
        __builtin_amdgcn_s_setprio(0);
        if (t + 2 < NT256) asm volatile("s_waitcnt vmcnt(4)" ::: "memory");
        else               asm volatile("s_waitcnt vmcnt(0)" ::: "memory");
        __builtin_amdgcn_s_barrier();               // end barrier == tile boundary
    }
}

// ---------------- G = xb @ Mt^T  (32768x1024), 256² snake ----------------
__global__ __launch_bounds__(512, 2) void gemm_g256(const bf16* __restrict__ xb,
                                                    const bf16* __restrict__ Mt,
                                                    bf16* __restrict__ G) {
    extern __shared__ char lds[];
    f32x4 acc[8][4];
    const int bx = blockIdx.x, by = blockIdx.y;
    gemm256_mainloop(xb + (size_t)by * 256 * 1024, Mt + (size_t)bx * 256 * 1024, lds, acc);
    const int lane = threadIdx.x & 63, wid = threadIdx.x >> 6;
    const int wm = wid >> 2, wn = wid & 3;
    const int row0 = by * 256 + wm * 128 + ((lane >> 4) << 2);
    const int col0 = bx * 256 + wn * 64 + (lane & 15);
#pragma unroll
    for (int mi = 0; mi < 8; ++mi)
#pragma unroll
        for (int ni = 0; ni < 4; ++ni)
#pragma unroll
            for (int r = 0; r < 4; ++r)
                G[(size_t)(row0 + mi * 16 + r) * 1024 + col0 + ni * 16] =
                    __float2bfloat16(acc[mi][ni][r]);
}

// ---------------- energy: E = G @ xb^T, P = fp8(exp(E)), lsum += rowsum(dec(P)) ----------------
__global__ __launch_bounds__(512, 2) void energy_fused256(const bf16* __restrict__ G,
                                                          const bf16* __restrict__ xb,
                                                          unsigned char* __restrict__ P,
                                                          float* __restrict__ lsum) {
    extern __shared__ char lds[];
    f32x4 acc[8][4];
    const int bx = blockIdx.x, by = blockIdx.y, bz = blockIdx.z;
    gemm256_mainloop(G + (size_t)(bz * 2048 + by * 256) * 1024,
                     xb + (size_t)(bz * 2048 + bx * 256) * 1024, lds, acc);
    const int lane = threadIdx.x & 63, wid = threadIdx.x >> 6;
    const int wm = wid >> 2, wn = wid & 3;
    const int q0 = bz * 2048 + by * 256 + wm * 128 + ((lane >> 4) << 2);
    const int k0 = bx * 256 + wn * 64 + (lane & 15);
#pragma unroll
    for (int mi = 0; mi < 8; ++mi) {
        float s[4] = {0.f, 0.f, 0.f, 0.f};
#pragma unroll
        for (int ni = 0; ni < 4; ++ni)
#pragma unroll
            for (int r = 0; r < 4; ++r) {
                float e = __expf(acc[mi][ni][r]);
                unsigned char c = f32_to_e4m3(e);
                P[(size_t)(q0 + mi * 16 + r) * 2048 + k0 + ni * 16] = c;
                s[r] += e4m3_to_f32(c);
            }
#pragma unroll
        for (int off = 1; off < 16; off <<= 1)
#pragma unroll
            for (int r = 0; r < 4; ++r) s[r] += __shfl_xor(s[r], off, 64);
        if ((lane & 15) == 0) {
#pragma unroll
            for (int r = 0; r < 4; ++r) atomicAdd(&lsum[q0 + mi * 16 + r], s[r]);
        }
    }
}

// ---------------- aw[b,k] = (1/S) sum_q dec(P[b,q,k]) / lsum[b,q] ----------------
__global__ __launch_bounds__(256) void colsum_kernel(const unsigned char* __restrict__ P,
                                                     const float* __restrict__ lsum,
                                                     float* __restrict__ aw) {
    const int b = blockIdx.y, qc = blockIdx.x, t = threadIdx.x;
    float acc[8] = {0.f, 0.f, 0.f, 0.f, 0.f, 0.f, 0.f, 0.f};
    const unsigned char* base = P + (size_t)(b * 2048 + qc * 128) * 2048 + t * 8;
    const float* ls = lsum + b * 2048 + qc * 128;
    for (int q = 0; q < 128; ++q) {
        float w = 1.0f / ls[q];
        uint2 v = *reinterpret_cast<const uint2*>(base + (size_t)q * 2048);
#if __has_builtin(__builtin_amdgcn_cvt_pk_f32_fp8)
        auto p0 = __builtin_amdgcn_cvt_pk_f32_fp8((int)v.x, false);
        auto p1 = __builtin_amdgcn_cvt_pk_f32_fp8((int)v.x, true);
        auto p2 = __builtin_amdgcn_cvt_pk_f32_fp8((int)v.y, false);
        auto p3 = __builtin_amdgcn_cvt_pk_f32_fp8((int)v.y, true);
        acc[0] += p0[0] * w; acc[1] += p0[1] * w;
        acc[2] += p1[0] * w; acc[3] += p1[1] * w;
        acc[4] += p2[0] * w; acc[5] += p2[1] * w;
        acc[6] += p3[0] * w; acc[7] += p3[1] * w;
#else
        unsigned char by8[8];
        *reinterpret_cast<uint2*>(by8) = v;
#pragma unroll
        for (int j = 0; j < 8; ++j) acc[j] += e4m3_to_f32(by8[j]) * w;
#endif
    }
#pragma unroll
    for (int j = 0; j < 8; ++j)
        atomicAdd(&aw[b * 2048 + t * 8 + j], acc[j] * (1.0f / 2048.0f));
}

// ---------------- t[b,h] = sum_k aw[b,k] * xb[b,k,h]  (bf16 x) ----------------
__global__ __launch_bounds__(256) void av_x_kernel(const float* __restrict__ aw,
                                                   const bf16* __restrict__ xb,
                                                   float* __restrict__ t) {
    const int b = blockIdx.y;
    const int kc = blockIdx.x;
    const int tid = threadIdx.x;
    float4 acc = {0.f, 0.f, 0.f, 0.f};
    const int k0 = kc * 128;
#pragma unroll 4
    for (int k = k0; k < k0 + 128; ++k) {
        float w = aw[b * 2048 + k];
        uint2 v = *reinterpret_cast<const uint2*>(xb + (size_t)(b * 2048 + k) * 1024 + tid * 4);
        acc.x += w * bf2f((unsigned short)(v.x & 0xffff));
        acc.y += w * bf2f((unsigned short)(v.x >> 16));
        acc.z += w * bf2f((unsigned short)(v.y & 0xffff));
        acc.w += w * bf2f((unsigned short)(v.y >> 16));
    }
    float* tp = t + b * 1024 + tid * 4;
    atomicAdd(tp + 0, acc.x); atomicAdd(tp + 1, acc.y);
    atomicAdd(tp + 2, acc.z); atomicAdd(tp + 3, acc.w);
}

// ---------------- context[b,o] = sum_h t[b,h] * W_v[o,h] ----------------
__global__ __launch_bounds__(256) void ctx_gemv_kernel(const float* __restrict__ t,
                                                       const float* __restrict__ wv,
                                                       float* __restrict__ ctx) {
    const int b = blockIdx.y;
    const int wid = threadIdx.x >> 6, lane = threadIdx.x & 63;
    const int o = blockIdx.x * 4 + wid;
    const float4* t4 = reinterpret_cast<const float4*>(t + b * 1024);
    const float4* w4 = reinterpret_cast<const float4*>(wv + (size_t)o * 1024);
    float s = 0.f;
#pragma unroll
    for (int j = lane; j < 256; j += 64) {
        float4 a = t4[j], w = w4[j];
        s += a.x * w.x + a.y * w.y + a.z * w.z + a.w * w.w;
    }
#pragma unroll
    for (int off = 1; off < 64; off <<= 1) s += __shfl_xor(s, off, 64);
    if (lane == 0) ctx[b * 1024 + o] = s;
}

__global__ void ws_too_small_kernel(float* out) {
    if (threadIdx.x == 0 && blockIdx.x == 0) out[0] = 12345.0f;
}

extern "C" void kernel_launch(void* const* d_in, const int* in_sizes, int n_in,
                              void* d_out, int out_size, void* d_ws, size_t ws_size,
                              hipStream_t stream) {
    const float* x  = (const float*)d_in[0];
    const float* wq = (const float*)d_in[1];
    const float* wk = (const float*)d_in[2];
    const float* wv = (const float*)d_in[3];
    float* out = (float*)d_out;
    float* ctx = out;           // 16*1024
    float* aw  = out + 16384;   // 16*2048

    if (ws_size < WS_NEED) {
        hipMemsetAsync(d_out, 0, (size_t)out_size * sizeof(float), stream);
        ws_too_small_kernel<<<1, 64, 0, stream>>>(out);
        return;
    }

    char* ws = (char*)d_ws;
    bf16* xb   = (bf16*)(ws + WS_XB);
    bf16* G    = (bf16*)(ws + WS_G);
    unsigned char* P = (unsigned char*)(ws + WS_P);
    bf16* wqT  = (bf16*)(ws + WS_WQT);
    bf16* wkT  = (bf16*)(ws + WS_WKT);
    bf16* Mt   = (bf16*)(ws + WS_MT);
    float* lsum = (float*)(ws + WS_LSUM);
    float* t    = (float*)(ws + WS_T);

    hipMemsetAsync(d_out, 0, (size_t)out_size * sizeof(float), stream);
    hipMemsetAsync(lsum, 0, 131072 + 65536, stream);  // lsum + t contiguous

    cast_x_kernel<<<2048, 256, 0, stream>>>(x, xb, (BB * SS * HH) / 4);
    transpose_w_kernel<<<dim3(16, 16, 2), 256, 0, stream>>>(wq, wk, wqT, wkT);

    gemm_mt64<<<dim3(16, 16), 256, 0, stream>>>(wkT, wqT, Mt);
    gemm_g256<<<dim3(4, 128), 512, 131072, stream>>>(xb, Mt, G);

    energy_fused256<<<dim3(8, 8, 16), 512, 131072, stream>>>(G, xb, P, lsum);
    colsum_kernel<<<dim3(16, 16), 256, 0, stream>>>(P, lsum, aw);

    av_x_kernel<<<dim3(16, 16), 256, 0, stream>>>(aw, xb, t);
    ctx_gemv_kernel<<<dim3(256, 16), 256, 0, stream>>>(t, wv, ctx);
}

// Round 5
// 322.932 us; speedup vs baseline: 2.0798x; 1.0044x over previous
//
#include <hip/hip_runtime.h>
#include <hip/hip_bf16.h>
#include <stdint.h>

// Problem constants
#define BB 16
#define SS 2048
#define HH 1024

using bf16 = __hip_bfloat16;
typedef __attribute__((ext_vector_type(8))) short short8;
typedef __attribute__((ext_vector_type(4))) float f32x4;

typedef unsigned int __attribute__((address_space(1))) as1_uint;
typedef unsigned int __attribute__((address_space(3))) as3_uint;

// ---------------- workspace layout (bytes) ----------------
static constexpr size_t WS_XB   = 0;          // bf16[16*2048*1024]
static constexpr size_t WS_G    = 67108864;   // bf16[32768*1024]
static constexpr size_t WS_P    = 134217728;  // fp8 [32768*2048]
static constexpr size_t WS_WQT  = 134217728;  // aliased, dead before P written
static constexpr size_t WS_WKT  = 136314880;
static constexpr size_t WS_MT   = 138412032;
static constexpr size_t WS_LSUM = 201326592;  // f32[32768]
static constexpr size_t WS_T    = 201457664;  // f32[16*1024]
static constexpr size_t WS_NEED = 201523200;

__device__ __forceinline__ void async_copy16(bf16* lds_dst, const bf16* gsrc) {
    __builtin_amdgcn_global_load_lds((const as1_uint*)gsrc, (as3_uint*)lds_dst, 16, 0, 0);
}

__device__ __forceinline__ float bf2f(unsigned short u) {
    union { unsigned i; float f; } v; v.i = (unsigned)u << 16; return v.f;
}

// ---------------- fp8 e4m3 encode/decode ----------------
__device__ __forceinline__ unsigned char f32_to_e4m3(float x) {
#if __has_builtin(__builtin_amdgcn_cvt_pk_fp8_f32)
    return (unsigned char)(__builtin_amdgcn_cvt_pk_fp8_f32(x, x, 0, false) & 0xff);
#else
    if (x >= 0.015625f) {
        union { float f; unsigned u; } v; v.f = x;
        int e = (v.u >> 23) & 0xff;
        unsigned m = v.u & 0x7fffff;
        unsigned mant = m >> 20;
        unsigned rem = m & 0xfffff;
        mant += (rem > 0x80000u) || (rem == 0x80000u && (mant & 1));
        int oe = e - 120;
        if (mant == 8) { mant = 0; oe += 1; }
        return (unsigned char)((oe << 3) | mant);
    }
    int code = (int)rintf(x * 512.0f);
    return (unsigned char)code;
#endif
}

__device__ __forceinline__ float e4m3_to_f32(unsigned char b) {
#if __has_builtin(__builtin_amdgcn_cvt_pk_f32_fp8)
    auto v = __builtin_amdgcn_cvt_pk_f32_fp8((int)b, false);
    return v[0];
#else
    int e = (b >> 3) & 15, m = b & 7;
    if (e) { union { unsigned u; float f; } v; v.u = ((unsigned)(e + 120) << 23) | ((unsigned)m << 20); return v.f; }
    return (float)m * 0.001953125f;
#endif
}

// ---------------- cast x -> bf16 ----------------
__global__ __launch_bounds__(256) void cast_x_kernel(const float* __restrict__ x,
                                                     bf16* __restrict__ xb, int n4) {
    int stride = gridDim.x * blockDim.x;
    for (int i = blockIdx.x * blockDim.x + threadIdx.x; i < n4; i += stride) {
        float4 v = reinterpret_cast<const float4*>(x)[i];
        union { bf16 h[4]; uint2 u; } p;
        p.h[0] = __float2bfloat16(v.x); p.h[1] = __float2bfloat16(v.y);
        p.h[2] = __float2bfloat16(v.z); p.h[3] = __float2bfloat16(v.w);
        reinterpret_cast<uint2*>(xb)[i] = p.u;
    }
}

// ---------------- transpose-cast W -> WT bf16 (i,o) ----------------
__global__ __launch_bounds__(256) void transpose_w_kernel(const float* __restrict__ wq,
                                                          const float* __restrict__ wk,
                                                          bf16* __restrict__ wqT,
                                                          bf16* __restrict__ wkT) {
    __shared__ float tile[64][65];
    const float* src = blockIdx.z ? wk : wq;
    bf16* dst = blockIdx.z ? wkT : wqT;
    const int o0 = blockIdx.y * 64, i0 = blockIdx.x * 64;
    const int tr = threadIdx.x >> 4;
    const int tc = (threadIdx.x & 15) * 4;
#pragma unroll
    for (int k = 0; k < 4; ++k) {
        float4 v = *reinterpret_cast<const float4*>(src + (size_t)(o0 + tr + k * 16) * 1024 + i0 + tc);
        tile[tr + k * 16][tc + 0] = v.x; tile[tr + k * 16][tc + 1] = v.y;
        tile[tr + k * 16][tc + 2] = v.z; tile[tr + k * 16][tc + 3] = v.w;
    }
    __syncthreads();
#pragma unroll
    for (int k = 0; k < 4; ++k) {
        int ri = tr + k * 16;
        union { bf16 h[4]; uint2 u; } p;
#pragma unroll
        for (int j = 0; j < 4; ++j) p.h[j] = __float2bfloat16(tile[tc + j][ri]);
        *reinterpret_cast<uint2*>(dst + (size_t)(i0 + ri) * 1024 + o0 + tc) = p.u;
    }
}

// ---------------- gemm_mt64: Mt[j][i] = (1/32) sum_o Wk[o,j]*Wq[o,i], 64x64 tiles ----------------
__global__ __launch_bounds__(256) void gemm_mt64(const bf16* __restrict__ wkT,
                                                 const bf16* __restrict__ wqT,
                                                 bf16* __restrict__ Mt) {
    __shared__ bf16 As[64 * 64], Bs[64 * 64];
    f32x4 acc[2][2];
#pragma unroll
    for (int m = 0; m < 2; ++m)
#pragma unroll
        for (int n = 0; n < 2; ++n) { acc[m][n][0]=0.f; acc[m][n][1]=0.f; acc[m][n][2]=0.f; acc[m][n][3]=0.f; }
    const int tid = threadIdx.x, wid = tid >> 6, lane = tid & 63;
    const int wm = wid >> 1, wn = wid & 1;
    const int srow = lane >> 3, scol = (lane & 7) * 8;
    const bf16* Ab = wkT + (size_t)blockIdx.y * 64 * 1024;
    const bf16* Bb = wqT + (size_t)blockIdx.x * 64 * 1024;
    for (int kt = 0; kt < 1024; kt += 64) {
#pragma unroll
        for (int i = 0; i < 2; ++i) {
            int row0 = i * 32 + wid * 8;  // wave-uniform
            async_copy16(As + row0 * 64, Ab + (size_t)(row0 + srow) * 1024 + kt + scol);
            async_copy16(Bs + row0 * 64, Bb + (size_t)(row0 + srow) * 1024 + kt + scol);
        }
        __syncthreads();
#pragma unroll
        for (int kk = 0; kk < 2; ++kk) {
            short8 a[2], b[2];
#pragma unroll
            for (int m = 0; m < 2; ++m)
                a[m] = *reinterpret_cast<const short8*>(
                    As + (wm * 32 + m * 16 + (lane & 15)) * 64 + kk * 32 + (lane >> 4) * 8);
#pragma unroll
            for (int n = 0; n < 2; ++n)
                b[n] = *reinterpret_cast<const short8*>(
                    Bs + (wn * 32 + n * 16 + (lane & 15)) * 64 + kk * 32 + (lane >> 4) * 8);
#pragma unroll
            for (int m = 0; m < 2; ++m)
#pragma unroll
                for (int n = 0; n < 2; ++n)
                    acc[m][n] = __builtin_amdgcn_mfma_f32_16x16x32_bf16(a[m], b[n], acc[m][n], 0, 0, 0);
        }
        __syncthreads();
    }
    const int row0 = blockIdx.y * 64 + wm * 32 + ((lane >> 4) << 2);
    const int col0 = blockIdx.x * 64 + wn * 32 + (lane & 15);
#pragma unroll
    for (int m = 0; m < 2; ++m)
#pragma unroll
        for (int n = 0; n < 2; ++n)
#pragma unroll
            for (int r = 0; r < 4; ++r)
                Mt[(size_t)(row0 + m * 16 + r) * 1024 + col0 + n * 16] =
                    __float2bfloat16(acc[m][n][r] * 0.03125f);
}

// ================= 256x256 2-phase snake mainloop (T2+T3+T4+T5) =================
// C[256x256] = A[256x1024] * B[256x1024]^T, row-major K-contiguous bf16, ld=1024.
// 512 threads = 8 waves (2M x 4N); per-wave C 128x64. Per K-tile (BK=64) 2 phases:
//   phA: read a0(8),b0(4),b1(4); stage A1,B1[t+1]->other buf; bar; lgkm0;
//        MFMA (0,0)+(0,1) [32]; bar
//   phB: read a1(8); stage A0,B0[t+2]->cur buf; bar; lgkm0;
//        MFMA (1,1)+(1,0) [32]; vmcnt(4); bar (=tile boundary)
// Region safety: each staged region's readers drained (lgkm0) before the barrier
// that precedes the stage issue. Boundary vmcnt(4) keeps the 4 newest (t+2 parts)
// in flight; waits t+1 complete. Swizzle: byte ^= ((row&7)<<4) == ((lane&7)<<4)
// on reads (row ≡ lane mod 8); inverse-applied on the per-lane global source.
static constexpr int NT256 = 16;  // K=1024 / BK=64

__device__ __forceinline__ void gemm256_mainloop(const bf16* __restrict__ Ag,
                                                 const bf16* __restrict__ Bg,
                                                 char* lds, f32x4 acc[8][4]) {
    const int tid = threadIdx.x;
    const int lane = tid & 63;
    const int wid = tid >> 6;
    const int wm = wid >> 2;   // 0..1
    const int wn = wid & 3;    // 0..3

#pragma unroll
    for (int m = 0; m < 8; ++m)
#pragma unroll
        for (int n = 0; n < 4; ++n) { acc[m][n][0]=0.f; acc[m][n][1]=0.f; acc[m][n][2]=0.f; acc[m][n][3]=0.f; }

    char* A0 = lds;            char* B0 = lds + 32768;
    char* A1 = lds + 65536;    char* B1 = lds + 98304;

    // ---- hoisted stage source offsets (elements) ----
    int soA[2], soB[2];   // [i]; +q*65536 (A) / +q*32768 (B) for region 1
    {
#pragma unroll
        for (int i = 0; i < 2; ++i) {
            int beta = (i * 512 + tid) * 16;
            int rho  = beta >> 7;
            int cs   = (beta & 127) ^ ((rho & 7) << 4);
            soA[i] = ((rho >> 6) * 128 + (rho & 63)) * 1024 + (cs >> 1);
            soB[i] = ((rho >> 5) * 64  + (rho & 31)) * 1024 + (cs >> 1);
        }
    }
    const int dstw = wid * 1024;  // wave-uniform lds dst base within region half

    // ---- hoisted ds_read byte offsets (lower halves; upper = ^16384, kk=1 = ^64) ----
    int roA[4], roB[2];
    {
        const int swz = (lane & 7) << 4;
        const int colb = (lane >> 4) * 16;
#pragma unroll
        for (int mi = 0; mi < 4; ++mi) {
            int row = wm * 64 + mi * 16 + (lane & 15);
            roA[mi] = (row * 128 + colb) ^ swz;
        }
#pragma unroll
        for (int ni = 0; ni < 2; ++ni) {
            int row = wn * 32 + ni * 16 + (lane & 15);
            roB[ni] = (row * 128 + colb) ^ swz;
        }
    }

#define STAGE_A256(buf, q, kt)                                                        \
    {                                                                                 \
        async_copy16((bf16*)((buf) + (q) * 16384 + dstw),                             \
                     Ag + soA[0] + (q) * 65536 + (kt) * 64);                          \
        async_copy16((bf16*)((buf) + (q) * 16384 + 8192 + dstw),                      \
                     Ag + soA[1] + (q) * 65536 + (kt) * 64);                          \
    }
#define STAGE_B256(buf, q, kt)                                                        \
    {                                                                                 \
        async_copy16((bf16*)((buf) + (q) * 16384 + dstw),                             \
                     Bg + soB[0] + (q) * 32768 + (kt) * 64);                          \
        async_copy16((bf16*)((buf) + (q) * 16384 + 8192 + dstw),                      \
                     Bg + soB[1] + (q) * 32768 + (kt) * 64);                          \
    }

    // Prologue: tile0 fully + tile1 {A0,B0}; wait the 8 oldest (tile0).
    STAGE_A256(A0, 0, 0); STAGE_A256(A0, 1, 0);
    STAGE_B256(B0, 0, 0); STAGE_B256(B0, 1, 0);
    STAGE_A256(A1, 0, 1); STAGE_B256(B1, 0, 1);
    asm volatile("s_waitcnt vmcnt(4)" ::: "memory");
    __builtin_amdgcn_s_barrier();

    short8 a[4][2], b0[2][2], b1[2][2];

#pragma unroll 1
    for (int t = 0; t < NT256; ++t) {
        char* As  = (t & 1) ? A1 : A0;
        char* Bs  = (t & 1) ? B1 : B0;
        char* Aso = (t & 1) ? A0 : A1;
        char* Bso = (t & 1) ? B0 : B1;

        // ======== phase A: quadrants (0,0) then (0,1) ========
#pragma unroll
        for (int mi = 0; mi < 4; ++mi) {
            a[mi][0] = *reinterpret_cast<const short8*>(As + roA[mi]);
            a[mi][1] = *reinterpret_cast<const short8*>(As + (roA[mi] ^ 64));
        }
#pragma unroll
        for (int ni = 0; ni < 2; ++ni) {
            b0[ni][0] = *reinterpret_cast<const short8*>(Bs + roB[ni]);
            b0[ni][1] = *reinterpret_cast<const short8*>(Bs + (roB[ni] ^ 64));
            b1[ni][0] = *reinterpret_cast<const short8*>(Bs + (roB[ni] + 16384));
            b1[ni][1] = *reinterpret_cast<const short8*>(Bs + ((roB[ni] ^ 64) + 16384));
        }
        if (t + 1 < NT256) { STAGE_A256(Aso, 1, t + 1); STAGE_B256(Bso, 1, t + 1); }
        __builtin_amdgcn_s_barrier();
        asm volatile("s_waitcnt lgkmcnt(0)" ::: "memory");
        __builtin_amdgcn_s_setprio(1);
#pragma unroll
        for (int mi = 0; mi < 4; ++mi)
#pragma unroll
            for (int ni = 0; ni < 2; ++ni)
#pragma unroll
                for (int kk = 0; kk < 2; ++kk)
                    acc[mi][ni] = __builtin_amdgcn_mfma_f32_16x16x32_bf16(
                        a[mi][kk], b0[ni][kk], acc[mi][ni], 0, 0, 0);
#pragma unroll
        for (int mi = 0; mi < 4; ++mi)
#pragma unroll
            for (int ni = 0; ni < 2; ++ni)
#pragma unroll
                for (int kk = 0; kk < 2; ++kk)
                    acc[mi][2 + ni] = __builtin_amdgcn_mfma_f32_16x16x32_bf16(
                        a[mi][kk], b1[ni][kk], acc[mi][2 + ni], 0, 0, 0);
        __builtin_amdgcn_s_setprio(0);
        __builtin_amdgcn_s_barrier();

        // ======== phase B: quadrants (1,1) then (1,0) ========
#pragma unroll
        for (int mi = 0; mi < 4; ++mi) {
            a[mi][0] = *reinterpret_cast<const short8*>(As + (roA[mi] + 16384));
            a[mi][1] = *reinterpret_cast<const short8*>(As + ((roA[mi] ^ 64) + 16384));
        }
        if (t + 2 < NT256) { STAGE_A256(As, 0, t + 2); STAGE_B256(Bs, 0, t + 2); }
        __builtin_amdgcn_s_barrier();
        asm volatile("s_waitcnt lgkmcnt(0)" ::: "memory");
        __builtin_amdgcn_s_setprio(1);
#pragma unroll
        for (int mi = 0; mi < 4; ++mi)
#pragma unroll
            for (int ni = 0; ni < 2; ++ni)
#pragma unroll
                for (int kk = 0; kk < 2; ++kk)
                    acc[4 + mi][2 + ni] = __builtin_amdgcn_mfma_f32_16x16x32_bf16(
                        a[mi][kk], b1[ni][kk], acc[4 + mi][2 + ni], 0, 0, 0);
#pragma unroll
        for (int mi = 0; mi < 4; ++mi)
#pragma unroll
            for (int ni = 0; ni < 2; ++ni)
#pragma unroll
                for (int kk = 0; kk < 2; ++kk)
                    acc[4 + mi][ni] = __builtin_amdgcn_mfma_f32_16x16x32_bf16(
                        a[mi][kk], b0[ni][kk], acc[4 + mi][ni], 0, 0, 0);
        __builtin_amdgcn_s_setprio(0);
        if (t + 2 < NT256) asm volatile("s_waitcnt vmcnt(4)" ::: "memory");
        else               asm volatile("s_waitcnt vmcnt(0)" ::: "memory");
        __builtin_amdgcn_s_barrier();   // tile boundary: tile t+1 fully landed
    }
#undef STAGE_A256
#undef STAGE_B256
}

// ---------------- G = xb @ Mt^T  (32768x1024), 256² 2-phase ----------------
__global__ __launch_bounds__(512, 2) void gemm_g256(const bf16* __restrict__ xb,
                                                    const bf16* __restrict__ Mt,
                                                    bf16* __restrict__ G) {
    extern __shared__ char lds[];
    f32x4 acc[8][4];
    const int bx = blockIdx.x, by = blockIdx.y;
    gemm256_mainloop(xb + (size_t)by * 256 * 1024, Mt + (size_t)bx * 256 * 1024, lds, acc);
    const int lane = threadIdx.x & 63, wid = threadIdx.x >> 6;
    const int wm = wid >> 2, wn = wid & 3;
    const int row0 = by * 256 + wm * 128 + ((lane >> 4) << 2);
    const int col0 = bx * 256 + wn * 64 + (lane & 15);
#pragma unroll
    for (int mi = 0; mi < 8; ++mi)
#pragma unroll
        for (int ni = 0; ni < 4; ++ni)
#pragma unroll
            for (int r = 0; r < 4; ++r)
                G[(size_t)(row0 + mi * 16 + r) * 1024 + col0 + ni * 16] =
                    __float2bfloat16(acc[mi][ni][r]);
}

// ---------------- energy: E = G @ xb^T, P = fp8(exp(E)), lsum += rowsum(dec(P)) ----------------
__global__ __launch_bounds__(512, 2) void energy_fused256(const bf16* __restrict__ G,
                                                          const bf16* __restrict__ xb,
                                                          unsigned char* __restrict__ P,
                                                          float* __restrict__ lsum) {
    extern __shared__ char lds[];
    f32x4 acc[8][4];
    const int bx = blockIdx.x, by = blockIdx.y, bz = blockIdx.z;
    gemm256_mainloop(G + (size_t)(bz * 2048 + by * 256) * 1024,
                     xb + (size_t)(bz * 2048 + bx * 256) * 1024, lds, acc);
    const int lane = threadIdx.x & 63, wid = threadIdx.x >> 6;
    const int wm = wid >> 2, wn = wid & 3;
    const int q0 = bz * 2048 + by * 256 + wm * 128 + ((lane >> 4) << 2);
    const int k0 = bx * 256 + wn * 64 + (lane & 15);
#pragma unroll
    for (int mi = 0; mi < 8; ++mi) {
        float s[4] = {0.f, 0.f, 0.f, 0.f};
#pragma unroll
        for (int ni = 0; ni < 4; ++ni)
#pragma unroll
            for (int r = 0; r < 4; ++r) {
                float e = __expf(acc[mi][ni][r]);
                unsigned char c = f32_to_e4m3(e);
                P[(size_t)(q0 + mi * 16 + r) * 2048 + k0 + ni * 16] = c;
                s[r] += e4m3_to_f32(c);
            }
#pragma unroll
        for (int off = 1; off < 16; off <<= 1)
#pragma unroll
            for (int r = 0; r < 4; ++r) s[r] += __shfl_xor(s[r], off, 64);
        if ((lane & 15) == 0) {
#pragma unroll
            for (int r = 0; r < 4; ++r) atomicAdd(&lsum[q0 + mi * 16 + r], s[r]);
        }
    }
}

// ---------------- aw[b,k] = (1/S) sum_q dec(P[b,q,k]) / lsum[b,q] ----------------
__global__ __launch_bounds__(256) void colsum_kernel(const unsigned char* __restrict__ P,
                                                     const float* __restrict__ lsum,
                                                     float* __restrict__ aw) {
    const int b = blockIdx.y, qc = blockIdx.x, t = threadIdx.x;
    float acc[8] = {0.f, 0.f, 0.f, 0.f, 0.f, 0.f, 0.f, 0.f};
    const unsigned char* base = P + (size_t)(b * 2048 + qc * 128) * 2048 + t * 8;
    const float* ls = lsum + b * 2048 + qc * 128;
    for (int q = 0; q < 128; ++q) {
        float w = 1.0f / ls[q];
        uint2 v = *reinterpret_cast<const uint2*>(base + (size_t)q * 2048);
#if __has_builtin(__builtin_amdgcn_cvt_pk_f32_fp8)
        auto p0 = __builtin_amdgcn_cvt_pk_f32_fp8((int)v.x, false);
        auto p1 = __builtin_amdgcn_cvt_pk_f32_fp8((int)v.x, true);
        auto p2 = __builtin_amdgcn_cvt_pk_f32_fp8((int)v.y, false);
        auto p3 = __builtin_amdgcn_cvt_pk_f32_fp8((int)v.y, true);
        acc[0] += p0[0] * w; acc[1] += p0[1] * w;
        acc[2] += p1[0] * w; acc[3] += p1[1] * w;
        acc[4] += p2[0] * w; acc[5] += p2[1] * w;
        acc[6] += p3[0] * w; acc[7] += p3[1] * w;
#else
        unsigned char by8[8];
        *reinterpret_cast<uint2*>(by8) = v;
#pragma unroll
        for (int j = 0; j < 8; ++j) acc[j] += e4m3_to_f32(by8[j]) * w;
#endif
    }
#pragma unroll
    for (int j = 0; j < 8; ++j)
        atomicAdd(&aw[b * 2048 + t * 8 + j], acc[j] * (1.0f / 2048.0f));
}

// ---------------- t[b,h] = sum_k aw[b,k] * xb[b,k,h]  (bf16 x) ----------------
__global__ __launch_bounds__(256) void av_x_kernel(const float* __restrict__ aw,
                                                   const bf16* __restrict__ xb,
                                                   float* __restrict__ t) {
    const int b = blockIdx.y;
    const int kc = blockIdx.x;
    const int tid = threadIdx.x;
    float4 acc = {0.f, 0.f, 0.f, 0.f};
    const int k0 = kc * 128;
#pragma unroll 4
    for (int k = k0; k < k0 + 128; ++k) {
        float w = aw[b * 2048 + k];
        uint2 v = *reinterpret_cast<const uint2*>(xb + (size_t)(b * 2048 + k) * 1024 + tid * 4);
        acc.x += w * bf2f((unsigned short)(v.x & 0xffff));
        acc.y += w * bf2f((unsigned short)(v.x >> 16));
        acc.z += w * bf2f((unsigned short)(v.y & 0xffff));
        acc.w += w * bf2f((unsigned short)(v.y >> 16));
    }
    float* tp = t + b * 1024 + tid * 4;
    atomicAdd(tp + 0, acc.x); atomicAdd(tp + 1, acc.y);
    atomicAdd(tp + 2, acc.z); atomicAdd(tp + 3, acc.w);
}

// ---------------- context[b,o] = sum_h t[b,h] * W_v[o,h] ----------------
__global__ __launch_bounds__(256) void ctx_gemv_kernel(const float* __restrict__ t,
                                                       const float* __restrict__ wv,
                                                       float* __restrict__ ctx) {
    const int b = blockIdx.y;
    const int wid = threadIdx.x >> 6, lane = threadIdx.x & 63;
    const int o = blockIdx.x * 4 + wid;
    const float4* t4 = reinterpret_cast<const float4*>(t + b * 1024);
    const float4* w4 = reinterpret_cast<const float4*>(wv + (size_t)o * 1024);
    float s = 0.f;
#pragma unroll
    for (int j = lane; j < 256; j += 64) {
        float4 a = t4[j], w = w4[j];
        s += a.x * w.x + a.y * w.y + a.z * w.z + a.w * w.w;
    }
#pragma unroll
    for (int off = 1; off < 64; off <<= 1) s += __shfl_xor(s, off, 64);
    if (lane == 0) ctx[b * 1024 + o] = s;
}

__global__ void ws_too_small_kernel(float* out) {
    if (threadIdx.x == 0 && blockIdx.x == 0) out[0] = 12345.0f;
}

extern "C" void kernel_launch(void* const* d_in, const int* in_sizes, int n_in,
                              void* d_out, int out_size, void* d_ws, size_t ws_size,
                              hipStream_t stream) {
    const float* x  = (const float*)d_in[0];
    const float* wq = (const float*)d_in[1];
    const float* wk = (const float*)d_in[2];
    const float* wv = (const float*)d_in[3];
    float* out = (float*)d_out;
    float* ctx = out;           // 16*1024
    float* aw  = out + 16384;   // 16*2048

    if (ws_size < WS_NEED) {
        hipMemsetAsync(d_out, 0, (size_t)out_size * sizeof(float), stream);
        ws_too_small_kernel<<<1, 64, 0, stream>>>(out);
        return;
    }

    char* ws = (char*)d_ws;
    bf16* xb   = (bf16*)(ws + WS_XB);
    bf16* G    = (bf16*)(ws + WS_G);
    unsigned char* P = (unsigned char*)(ws + WS_P);
    bf16* wqT  = (bf16*)(ws + WS_WQT);
    bf16* wkT  = (bf16*)(ws + WS_WKT);
    bf16* Mt   = (bf16*)(ws + WS_MT);
    float* lsum = (float*)(ws + WS_LSUM);
    float* t    = (float*)(ws + WS_T);

    hipMemsetAsync(d_out, 0, (size_t)out_size * sizeof(float), stream);
    hipMemsetAsync(lsum, 0, 131072 + 65536, stream);  // lsum + t contiguous

    cast_x_kernel<<<2048, 256, 0, stream>>>(x, xb, (BB * SS * HH) / 4);
    transpose_w_kernel<<<dim3(16, 16, 2), 256, 0, stream>>>(wq, wk, wqT, wkT);

    gemm_mt64<<<dim3(16, 16), 256, 0, stream>>>(wkT, wqT, Mt);
    gemm_g256<<<dim3(4, 128), 512, 131072, stream>>>(xb, Mt, G);

    energy_fused256<<<dim3(8, 8, 16), 512, 131072, stream>>>(G, xb, P, lsum);
    colsum_kernel<<<dim3(16, 16), 256, 0, stream>>>(P, lsum, aw);

    av_x_kernel<<<dim3(16, 16), 256, 0, stream>>>(aw, xb, t);
    ctx_gemv_kernel<<<dim3(256, 16), 256, 0, stream>>>(t, wv, ctx);
}

// Round 6
// 316.963 us; speedup vs baseline: 2.1189x; 1.0188x over previous
//
#include <hip/hip_runtime.h>
#include <hip/hip_bf16.h>
#include <stdint.h>

// Problem constants
#define BB 16
#define SS 2048
#define HH 1024

using bf16 = __hip_bfloat16;
typedef __attribute__((ext_vector_type(8))) short short8;
typedef __attribute__((ext_vector_type(4))) float f32x4;

typedef unsigned int __attribute__((address_space(1))) as1_uint;
typedef unsigned int __attribute__((address_space(3))) as3_uint;

// ---------------- workspace layout (bytes) ----------------
static constexpr size_t WS_XB   = 0;          // bf16[16*2048*1024]
static constexpr size_t WS_G    = 67108864;   // bf16[32768*1024]
static constexpr size_t WS_P    = 134217728;  // fp8 [32768*2048]
static constexpr size_t WS_WQT  = 134217728;  // aliased, dead before P written
static constexpr size_t WS_WKT  = 136314880;
static constexpr size_t WS_MT   = 138412032;
static constexpr size_t WS_LSUM = 201326592;  // f32[32768]
static constexpr size_t WS_T    = 201457664;  // f32[16*1024]
static constexpr size_t WS_NEED = 201523200;

__device__ __forceinline__ void async_copy16(bf16* lds_dst, const bf16* gsrc) {
    __builtin_amdgcn_global_load_lds((const as1_uint*)gsrc, (as3_uint*)lds_dst, 16, 0, 0);
}

__device__ __forceinline__ float bf2f(unsigned short u) {
    union { unsigned i; float f; } v; v.i = (unsigned)u << 16; return v.f;
}

// ---------------- fp8 e4m3 encode/decode ----------------
__device__ __forceinline__ unsigned char f32_to_e4m3(float x) {
#if __has_builtin(__builtin_amdgcn_cvt_pk_fp8_f32)
    return (unsigned char)(__builtin_amdgcn_cvt_pk_fp8_f32(x, x, 0, false) & 0xff);
#else
    if (x >= 0.015625f) {
        union { float f; unsigned u; } v; v.f = x;
        int e = (v.u >> 23) & 0xff;
        unsigned m = v.u & 0x7fffff;
        unsigned mant = m >> 20;
        unsigned rem = m & 0xfffff;
        mant += (rem > 0x80000u) || (rem == 0x80000u && (mant & 1));
        int oe = e - 120;
        if (mant == 8) { mant = 0; oe += 1; }
        return (unsigned char)((oe << 3) | mant);
    }
    int code = (int)rintf(x * 512.0f);
    return (unsigned char)code;
#endif
}

__device__ __forceinline__ float e4m3_to_f32(unsigned char b) {
#if __has_builtin(__builtin_amdgcn_cvt_pk_f32_fp8)
    auto v = __builtin_amdgcn_cvt_pk_f32_fp8((int)b, false);
    return v[0];
#else
    int e = (b >> 3) & 15, m = b & 7;
    if (e) { union { unsigned u; float f; } v; v.u = ((unsigned)(e + 120) << 23) | ((unsigned)m << 20); return v.f; }
    return (float)m * 0.001953125f;
#endif
}

// ---------------- cast x -> bf16 ----------------
__global__ __launch_bounds__(256) void cast_x_kernel(const float* __restrict__ x,
                                                     bf16* __restrict__ xb, int n4) {
    int stride = gridDim.x * blockDim.x;
    for (int i = blockIdx.x * blockDim.x + threadIdx.x; i < n4; i += stride) {
        float4 v = reinterpret_cast<const float4*>(x)[i];
        union { bf16 h[4]; uint2 u; } p;
        p.h[0] = __float2bfloat16(v.x); p.h[1] = __float2bfloat16(v.y);
        p.h[2] = __float2bfloat16(v.z); p.h[3] = __float2bfloat16(v.w);
        reinterpret_cast<uint2*>(xb)[i] = p.u;
    }
}

// ---------------- transpose-cast W -> WT bf16 (i,o) ----------------
__global__ __launch_bounds__(256) void transpose_w_kernel(const float* __restrict__ wq,
                                                          const float* __restrict__ wk,
                                                          bf16* __restrict__ wqT,
                                                          bf16* __restrict__ wkT) {
    __shared__ float tile[64][65];
    const float* src = blockIdx.z ? wk : wq;
    bf16* dst = blockIdx.z ? wkT : wqT;
    const int o0 = blockIdx.y * 64, i0 = blockIdx.x * 64;
    const int tr = threadIdx.x >> 4;
    const int tc = (threadIdx.x & 15) * 4;
#pragma unroll
    for (int k = 0; k < 4; ++k) {
        float4 v = *reinterpret_cast<const float4*>(src + (size_t)(o0 + tr + k * 16) * 1024 + i0 + tc);
        tile[tr + k * 16][tc + 0] = v.x; tile[tr + k * 16][tc + 1] = v.y;
        tile[tr + k * 16][tc + 2] = v.z; tile[tr + k * 16][tc + 3] = v.w;
    }
    __syncthreads();
#pragma unroll
    for (int k = 0; k < 4; ++k) {
        int ri = tr + k * 16;
        union { bf16 h[4]; uint2 u; } p;
#pragma unroll
        for (int j = 0; j < 4; ++j) p.h[j] = __float2bfloat16(tile[tc + j][ri]);
        *reinterpret_cast<uint2*>(dst + (size_t)(i0 + ri) * 1024 + o0 + tc) = p.u;
    }
}

// ---------------- gemm_mt64: Mt[j][i] = (1/32) sum_o Wk[o,j]*Wq[o,i], 64x64 tiles ----------------
__global__ __launch_bounds__(256) void gemm_mt64(const bf16* __restrict__ wkT,
                                                 const bf16* __restrict__ wqT,
                                                 bf16* __restrict__ Mt) {
    __shared__ bf16 As[64 * 64], Bs[64 * 64];
    f32x4 acc[2][2];
#pragma unroll
    for (int m = 0; m < 2; ++m)
#pragma unroll
        for (int n = 0; n < 2; ++n) { acc[m][n][0]=0.f; acc[m][n][1]=0.f; acc[m][n][2]=0.f; acc[m][n][3]=0.f; }
    const int tid = threadIdx.x, wid = tid >> 6, lane = tid & 63;
    const int wm = wid >> 1, wn = wid & 1;
    const int srow = lane >> 3, scol = (lane & 7) * 8;
    const bf16* Ab = wkT + (size_t)blockIdx.y * 64 * 1024;
    const bf16* Bb = wqT + (size_t)blockIdx.x * 64 * 1024;
    for (int kt = 0; kt < 1024; kt += 64) {
#pragma unroll
        for (int i = 0; i < 2; ++i) {
            int row0 = i * 32 + wid * 8;  // wave-uniform
            async_copy16(As + row0 * 64, Ab + (size_t)(row0 + srow) * 1024 + kt + scol);
            async_copy16(Bs + row0 * 64, Bb + (size_t)(row0 + srow) * 1024 + kt + scol);
        }
        __syncthreads();
#pragma unroll
        for (int kk = 0; kk < 2; ++kk) {
            short8 a[2], b[2];
#pragma unroll
            for (int m = 0; m < 2; ++m)
                a[m] = *reinterpret_cast<const short8*>(
                    As + (wm * 32 + m * 16 + (lane & 15)) * 64 + kk * 32 + (lane >> 4) * 8);
#pragma unroll
            for (int n = 0; n < 2; ++n)
                b[n] = *reinterpret_cast<const short8*>(
                    Bs + (wn * 32 + n * 16 + (lane & 15)) * 64 + kk * 32 + (lane >> 4) * 8);
#pragma unroll
            for (int m = 0; m < 2; ++m)
#pragma unroll
                for (int n = 0; n < 2; ++n)
                    acc[m][n] = __builtin_amdgcn_mfma_f32_16x16x32_bf16(a[m], b[n], acc[m][n], 0, 0, 0);
        }
        __syncthreads();
    }
    const int row0 = blockIdx.y * 64 + wm * 32 + ((lane >> 4) << 2);
    const int col0 = blockIdx.x * 64 + wn * 32 + (lane & 15);
#pragma unroll
    for (int m = 0; m < 2; ++m)
#pragma unroll
        for (int n = 0; n < 2; ++n)
#pragma unroll
            for (int r = 0; r < 4; ++r)
                Mt[(size_t)(row0 + m * 16 + r) * 1024 + col0 + n * 16] =
                    __float2bfloat16(acc[m][n][r] * 0.03125f);
}

// ================= 256x256 overlap mainloop (T2+T4+T5 + compiler fine-grained lgkm) =================
// C[256x256] = A[256x1024] * B[256x1024]^T, row-major K-contiguous bf16, ld=1024.
// 512 threads = 8 waves (2M x 4N); per-wave C 128x64. Per K-tile (BK=64):
//   top:  issue ds_reads b0(4),a0(8),b1(4); stage A1,B1[t+1]->other buf;
//         MFMA Q00+Q01 (compiler-scheduled fine-grained lgkmcnt -> reads stream under MFMA);
//         sched_barrier(0); mid-barrier  (all waves' q0-region reads complete)
//   bot:  stage A0,B0[t+2]->cur buf q0 regions; issue ds_reads a1(8);
//         MFMA Q11+Q10; sched_barrier(0); vmcnt(4); boundary barrier.
// Staging schedule/depth identical to R5 (race-free): boundary vmcnt(4) keeps the 4
// newest (t+2 parts) in flight; tile t+1 fully landed at the boundary.
// NO explicit lgkmcnt(0) before MFMA clusters: the compiler interleaves counted
// lgkm waits with the MFMAs (m97 evidence), overlapping LDS pipe with MFMA pipe.
static constexpr int NT256 = 16;  // K=1024 / BK=64

__device__ __forceinline__ void gemm256_mainloop(const bf16* __restrict__ Ag,
                                                 const bf16* __restrict__ Bg,
                                                 char* lds, f32x4 acc[8][4]) {
    const int tid = threadIdx.x;
    const int lane = tid & 63;
    const int wid = tid >> 6;
    const int wm = wid >> 2;   // 0..1
    const int wn = wid & 3;    // 0..3

#pragma unroll
    for (int m = 0; m < 8; ++m)
#pragma unroll
        for (int n = 0; n < 4; ++n) { acc[m][n][0]=0.f; acc[m][n][1]=0.f; acc[m][n][2]=0.f; acc[m][n][3]=0.f; }

    char* A0 = lds;            char* B0 = lds + 32768;
    char* A1 = lds + 65536;    char* B1 = lds + 98304;

    // ---- hoisted stage source offsets (elements) ----
    int soA[2], soB[2];
    {
#pragma unroll
        for (int i = 0; i < 2; ++i) {
            int beta = (i * 512 + tid) * 16;
            int rho  = beta >> 7;
            int cs   = (beta & 127) ^ ((rho & 7) << 4);
            soA[i] = ((rho >> 6) * 128 + (rho & 63)) * 1024 + (cs >> 1);
            soB[i] = ((rho >> 5) * 64  + (rho & 31)) * 1024 + (cs >> 1);
        }
    }
    const int dstw = wid * 1024;  // wave-uniform lds dst base within region half

    // ---- hoisted ds_read byte offsets (lower halves; upper = +16384, kk=1 = ^64) ----
    int roA[4], roB[2];
    {
        const int swz = (lane & 7) << 4;
        const int colb = (lane >> 4) * 16;
#pragma unroll
        for (int mi = 0; mi < 4; ++mi) {
            int row = wm * 64 + mi * 16 + (lane & 15);
            roA[mi] = (row * 128 + colb) ^ swz;
        }
#pragma unroll
        for (int ni = 0; ni < 2; ++ni) {
            int row = wn * 32 + ni * 16 + (lane & 15);
            roB[ni] = (row * 128 + colb) ^ swz;
        }
    }

#define STAGE_A256(buf, q, kt)                                                        \
    {                                                                                 \
        async_copy16((bf16*)((buf) + (q) * 16384 + dstw),                             \
                     Ag + soA[0] + (q) * 65536 + (kt) * 64);                          \
        async_copy16((bf16*)((buf) + (q) * 16384 + 8192 + dstw),                      \
                     Ag + soA[1] + (q) * 65536 + (kt) * 64);                          \
    }
#define STAGE_B256(buf, q, kt)                                                        \
    {                                                                                 \
        async_copy16((bf16*)((buf) + (q) * 16384 + dstw),                             \
                     Bg + soB[0] + (q) * 32768 + (kt) * 64);                          \
        async_copy16((bf16*)((buf) + (q) * 16384 + 8192 + dstw),                      \
                     Bg + soB[1] + (q) * 32768 + (kt) * 64);                          \
    }

    // Prologue: tile0 fully + tile1 {A0,B0}; wait the 8 oldest (tile0).
    STAGE_A256(A0, 0, 0); STAGE_A256(A0, 1, 0);
    STAGE_B256(B0, 0, 0); STAGE_B256(B0, 1, 0);
    STAGE_A256(A1, 0, 1); STAGE_B256(B1, 0, 1);
    asm volatile("s_waitcnt vmcnt(4)" ::: "memory");
    __builtin_amdgcn_s_barrier();

    short8 a[4][2], b0[2][2], b1[2][2];

#pragma unroll 1
    for (int t = 0; t < NT256; ++t) {
        char* As  = (t & 1) ? A1 : A0;
        char* Bs  = (t & 1) ? B1 : B0;
        char* Aso = (t & 1) ? A0 : A1;
        char* Bso = (t & 1) ? B0 : B1;

        // ======== top half: quadrants (0,0) then (0,1) ========
        // read order: b0 first, then a0 (mi-major), then b1 -> first MFMA unlocks after 6 reads
#pragma unroll
        for (int ni = 0; ni < 2; ++ni) {
            b0[ni][0] = *reinterpret_cast<const short8*>(Bs + roB[ni]);
            b0[ni][1] = *reinterpret_cast<const short8*>(Bs + (roB[ni] ^ 64));
        }
#pragma unroll
        for (int mi = 0; mi < 4; ++mi) {
            a[mi][0] = *reinterpret_cast<const short8*>(As + roA[mi]);
            a[mi][1] = *reinterpret_cast<const short8*>(As + (roA[mi] ^ 64));
        }
#pragma unroll
        for (int ni = 0; ni < 2; ++ni) {
            b1[ni][0] = *reinterpret_cast<const short8*>(Bs + (roB[ni] + 16384));
            b1[ni][1] = *reinterpret_cast<const short8*>(Bs + ((roB[ni] ^ 64) + 16384));
        }
        if (t + 1 < NT256) { STAGE_A256(Aso, 1, t + 1); STAGE_B256(Bso, 1, t + 1); }
        __builtin_amdgcn_s_setprio(1);
#pragma unroll
        for (int mi = 0; mi < 4; ++mi)
#pragma unroll
            for (int ni = 0; ni < 2; ++ni)
#pragma unroll
                for (int kk = 0; kk < 2; ++kk)
                    acc[mi][ni] = __builtin_amdgcn_mfma_f32_16x16x32_bf16(
                        a[mi][kk], b0[ni][kk], acc[mi][ni], 0, 0, 0);
#pragma unroll
        for (int mi = 0; mi < 4; ++mi)
#pragma unroll
            for (int ni = 0; ni < 2; ++ni)
#pragma unroll
                for (int kk = 0; kk < 2; ++kk)
                    acc[mi][2 + ni] = __builtin_amdgcn_mfma_f32_16x16x32_bf16(
                        a[mi][kk], b1[ni][kk], acc[mi][2 + ni], 0, 0, 0);
        __builtin_amdgcn_s_setprio(0);
        __builtin_amdgcn_sched_barrier(0);   // pin MFMAs + their lgkm waits above the barrier
        __builtin_amdgcn_s_barrier();        // all waves' q0-region reads complete

        // ======== bottom half: quadrants (1,1) then (1,0) ========
        if (t + 2 < NT256) { STAGE_A256(As, 0, t + 2); STAGE_B256(Bs, 0, t + 2); }
#pragma unroll
        for (int mi = 0; mi < 4; ++mi) {
            a[mi][0] = *reinterpret_cast<const short8*>(As + (roA[mi] + 16384));
            a[mi][1] = *reinterpret_cast<const short8*>(As + ((roA[mi] ^ 64) + 16384));
        }
        __builtin_amdgcn_s_setprio(1);
#pragma unroll
        for (int mi = 0; mi < 4; ++mi)
#pragma unroll
            for (int ni = 0; ni < 2; ++ni)
#pragma unroll
                for (int kk = 0; kk < 2; ++kk)
                    acc[4 + mi][2 + ni] = __builtin_amdgcn_mfma_f32_16x16x32_bf16(
                        a[mi][kk], b1[ni][kk], acc[4 + mi][2 + ni], 0, 0, 0);
#pragma unroll
        for (int mi = 0; mi < 4; ++mi)
#pragma unroll
            for (int ni = 0; ni < 2; ++ni)
#pragma unroll
                for (int kk = 0; kk < 2; ++kk)
                    acc[4 + mi][ni] = __builtin_amdgcn_mfma_f32_16x16x32_bf16(
                        a[mi][kk], b0[ni][kk], acc[4 + mi][ni], 0, 0, 0);
        __builtin_amdgcn_s_setprio(0);
        __builtin_amdgcn_sched_barrier(0);   // pin a1 reads/waits above the boundary
        if (t + 2 < NT256) asm volatile("s_waitcnt vmcnt(4)" ::: "memory");
        else               asm volatile("s_waitcnt vmcnt(0)" ::: "memory");
        __builtin_amdgcn_s_barrier();        // tile boundary: tile t+1 fully landed
    }
#undef STAGE_A256
#undef STAGE_B256
}

// ---------------- G = xb @ Mt^T  (32768x1024), 256² overlap ----------------
__global__ __launch_bounds__(512, 2) void gemm_g256(const bf16* __restrict__ xb,
                                                    const bf16* __restrict__ Mt,
                                                    bf16* __restrict__ G) {
    extern __shared__ char lds[];
    f32x4 acc[8][4];
    const int bx = blockIdx.x, by = blockIdx.y;
    gemm256_mainloop(xb + (size_t)by * 256 * 1024, Mt + (size_t)bx * 256 * 1024, lds, acc);
    const int lane = threadIdx.x & 63, wid = threadIdx.x >> 6;
    const int wm = wid >> 2, wn = wid & 3;
    const int row0 = by * 256 + wm * 128 + ((lane >> 4) << 2);
    const int col0 = bx * 256 + wn * 64 + (lane & 15);
#pragma unroll
    for (int mi = 0; mi < 8; ++mi)
#pragma unroll
        for (int ni = 0; ni < 4; ++ni)
#pragma unroll
            for (int r = 0; r < 4; ++r)
                G[(size_t)(row0 + mi * 16 + r) * 1024 + col0 + ni * 16] =
                    __float2bfloat16(acc[mi][ni][r]);
}

// ---------------- energy: E = G @ xb^T, P = fp8(exp(E)), lsum += rowsum(dec(P)) ----------------
__global__ __launch_bounds__(512, 2) void energy_fused256(const bf16* __restrict__ G,
                                                          const bf16* __restrict__ xb,
                                                          unsigned char* __restrict__ P,
                                                          float* __restrict__ lsum) {
    extern __shared__ char lds[];
    f32x4 acc[8][4];
    const int bx = blockIdx.x, by = blockIdx.y, bz = blockIdx.z;
    gemm256_mainloop(G + (size_t)(bz * 2048 + by * 256) * 1024,
                     xb + (size_t)(bz * 2048 + bx * 256) * 1024, lds, acc);
    const int lane = threadIdx.x & 63, wid = threadIdx.x >> 6;
    const int wm = wid >> 2, wn = wid & 3;
    const int q0 = bz * 2048 + by * 256 + wm * 128 + ((lane >> 4) << 2);
    const int k0 = bx * 256 + wn * 64 + (lane & 15);
#pragma unroll
    for (int mi = 0; mi < 8; ++mi) {
        float s[4] = {0.f, 0.f, 0.f, 0.f};
#pragma unroll
        for (int ni = 0; ni < 4; ++ni)
#pragma unroll
            for (int r = 0; r < 4; ++r) {
                float e = __expf(acc[mi][ni][r]);
                unsigned char c = f32_to_e4m3(e);
                P[(size_t)(q0 + mi * 16 + r) * 2048 + k0 + ni * 16] = c;
                s[r] += e4m3_to_f32(c);
            }
#pragma unroll
        for (int off = 1; off < 16; off <<= 1)
#pragma unroll
            for (int r = 0; r < 4; ++r) s[r] += __shfl_xor(s[r], off, 64);
        if ((lane & 15) == 0) {
#pragma unroll
            for (int r = 0; r < 4; ++r) atomicAdd(&lsum[q0 + mi * 16 + r], s[r]);
        }
    }
}

// ---------------- aw[b,k] = (1/S) sum_q dec(P[b,q,k]) / lsum[b,q] ----------------
__global__ __launch_bounds__(256) void colsum_kernel(const unsigned char* __restrict__ P,
                                                     const float* __restrict__ lsum,
                                                     float* __restrict__ aw) {
    const int b = blockIdx.y, qc = blockIdx.x, t = threadIdx.x;
    float acc[8] = {0.f, 0.f, 0.f, 0.f, 0.f, 0.f, 0.f, 0.f};
    const unsigned char* base = P + (size_t)(b * 2048 + qc * 128) * 2048 + t * 8;
    const float* ls = lsum + b * 2048 + qc * 128;
    for (int q = 0; q < 128; ++q) {
        float w = 1.0f / ls[q];
        uint2 v = *reinterpret_cast<const uint2*>(base + (size_t)q * 2048);
#if __has_builtin(__builtin_amdgcn_cvt_pk_f32_fp8)
        auto p0 = __builtin_amdgcn_cvt_pk_f32_fp8((int)v.x, false);
        auto p1 = __builtin_amdgcn_cvt_pk_f32_fp8((int)v.x, true);
        auto p2 = __builtin_amdgcn_cvt_pk_f32_fp8((int)v.y, false);
        auto p3 = __builtin_amdgcn_cvt_pk_f32_fp8((int)v.y, true);
        acc[0] += p0[0] * w; acc[1] += p0[1] * w;
        acc[2] += p1[0] * w; acc[3] += p1[1] * w;
        acc[4] += p2[0] * w; acc[5] += p2[1] * w;
        acc[6] += p3[0] * w; acc[7] += p3[1] * w;
#else
        unsigned char by8[8];
        *reinterpret_cast<uint2*>(by8) = v;
#pragma unroll
        for (int j = 0; j < 8; ++j) acc[j] += e4m3_to_f32(by8[j]) * w;
#endif
    }
#pragma unroll
    for (int j = 0; j < 8; ++j)
        atomicAdd(&aw[b * 2048 + t * 8 + j], acc[j] * (1.0f / 2048.0f));
}

// ---------------- t[b,h] = sum_k aw[b,k] * xb[b,k,h]  (bf16 x) ----------------
__global__ __launch_bounds__(256) void av_x_kernel(const float* __restrict__ aw,
                                                   const bf16* __restrict__ xb,
                                                   float* __restrict__ t) {
    const int b = blockIdx.y;
    const int kc = blockIdx.x;
    const int tid = threadIdx.x;
    float4 acc = {0.f, 0.f, 0.f, 0.f};
    const int k0 = kc * 128;
#pragma unroll 4
    for (int k = k0; k < k0 + 128; ++k) {
        float w = aw[b * 2048 + k];
        uint2 v = *reinterpret_cast<const uint2*>(xb + (size_t)(b * 2048 + k) * 1024 + tid * 4);
        acc.x += w * bf2f((unsigned short)(v.x & 0xffff));
        acc.y += w * bf2f((unsigned short)(v.x >> 16));
        acc.z += w * bf2f((unsigned short)(v.y & 0xffff));
        acc.w += w * bf2f((unsigned short)(v.y >> 16));
    }
    float* tp = t + b * 1024 + tid * 4;
    atomicAdd(tp + 0, acc.x); atomicAdd(tp + 1, acc.y);
    atomicAdd(tp + 2, acc.z); atomicAdd(tp + 3, acc.w);
}

// ---------------- context[b,o] = sum_h t[b,h] * W_v[o,h] ----------------
__global__ __launch_bounds__(256) void ctx_gemv_kernel(const float* __restrict__ t,
                                                       const float* __restrict__ wv,
                                                       float* __restrict__ ctx) {
    const int b = blockIdx.y;
    const int wid = threadIdx.x >> 6, lane = threadIdx.x & 63;
    const int o = blockIdx.x * 4 + wid;
    const float4* t4 = reinterpret_cast<const float4*>(t + b * 1024);
    const float4* w4 = reinterpret_cast<const float4*>(wv + (size_t)o * 1024);
    float s = 0.f;
#pragma unroll
    for (int j = lane; j < 256; j += 64) {
        float4 a = t4[j], w = w4[j];
        s += a.x * w.x + a.y * w.y + a.z * w.z + a.w * w.w;
    }
#pragma unroll
    for (int off = 1; off < 64; off <<= 1) s += __shfl_xor(s, off, 64);
    if (lane == 0) ctx[b * 1024 + o] = s;
}

__global__ void ws_too_small_kernel(float* out) {
    if (threadIdx.x == 0 && blockIdx.x == 0) out[0] = 12345.0f;
}

extern "C" void kernel_launch(void* const* d_in, const int* in_sizes, int n_in,
                              void* d_out, int out_size, void* d_ws, size_t ws_size,
                              hipStream_t stream) {
    const float* x  = (const float*)d_in[0];
    const float* wq = (const float*)d_in[1];
    const float* wk = (const float*)d_in[2];
    const float* wv = (const float*)d_in[3];
    float* out = (float*)d_out;
    float* ctx = out;           // 16*1024
    float* aw  = out + 16384;   // 16*2048

    if (ws_size < WS_NEED) {
        hipMemsetAsync(d_out, 0, (size_t)out_size * sizeof(float), stream);
        ws_too_small_kernel<<<1, 64, 0, stream>>>(out);
        return;
    }

    char* ws = (char*)d_ws;
    bf16* xb   = (bf16*)(ws + WS_XB);
    bf16* G    = (bf16*)(ws + WS_G);
    unsigned char* P = (unsigned char*)(ws + WS_P);
    bf16* wqT  = (bf16*)(ws + WS_WQT);
    bf16* wkT  = (bf16*)(ws + WS_WKT);
    bf16* Mt   = (bf16*)(ws + WS_MT);
    float* lsum = (float*)(ws + WS_LSUM);
    float* t    = (float*)(ws + WS_T);

    hipMemsetAsync(d_out, 0, (size_t)out_size * sizeof(float), stream);
    hipMemsetAsync(lsum, 0, 131072 + 65536, stream);  // lsum + t contiguous

    cast_x_kernel<<<2048, 256, 0, stream>>>(x, xb, (BB * SS * HH) / 4);
    transpose_w_kernel<<<dim3(16, 16, 2), 256, 0, stream>>>(wq, wk, wqT, wkT);

    gemm_mt64<<<dim3(16, 16), 256, 0, stream>>>(wkT, wqT, Mt);
    gemm_g256<<<dim3(4, 128), 512, 131072, stream>>>(xb, Mt, G);

    energy_fused256<<<dim3(8, 8, 16), 512, 131072, stream>>>(G, xb, P, lsum);
    colsum_kernel<<<dim3(16, 16), 256, 0, stream>>>(P, lsum, aw);

    av_x_kernel<<<dim3(16, 16), 256, 0, stream>>>(aw, xb, t);
    ctx_gemv_kernel<<<dim3(256, 16), 256, 0, stream>>>(t, wv, ctx);
}